// Round 8
// baseline (858.650 us; speedup 1.0000x reference)
//
#include <hip/hip_runtime.h>
#include <math.h>

#define DEV __device__ __forceinline__

DEV float geluf(float x){ return 0.5f*x*(1.0f+erff(x*0.7071067811865476f)); }
DEV float siluf(float x){ return x/(1.0f+expf(-x)); }
DEV float softplusf(float x){ return fmaxf(x,0.0f)+log1pf(expf(-fabsf(x))); }
DEV unsigned short f2bf(float f){
  unsigned int u = __float_as_uint(f);
  unsigned int r = (u + 0x7fffu + ((u>>16)&1u)) >> 16;
  return (unsigned short)r;
}

typedef __attribute__((ext_vector_type(8))) short short8;
typedef __attribute__((ext_vector_type(4))) float f32x4;

// ---------------- conv1: (8,12,4096) -> (8,192,2048), k=5 s=2 p=2, gelu+bn ----------------
__global__ void conv1_k(const float* __restrict__ x, const float* __restrict__ w,
                        const float* __restrict__ bias,
                        const float* __restrict__ g, const float* __restrict__ bb,
                        const float* __restrict__ m, const float* __restrict__ v,
                        float* __restrict__ out){
  int t  = blockIdx.x*256 + threadIdx.x;
  int og = blockIdx.y;
  int b  = blockIdx.z;
  const float* xb = x + (size_t)b*12*4096;
  float acc[8];
  #pragma unroll
  for(int oo=0;oo<8;++oo) acc[oo] = bias[og*8+oo];
  for(int i=0;i<12;++i){
    float xv[5];
    #pragma unroll
    for(int k=0;k<5;++k){
      int src = 2*t + k - 2;
      xv[k] = (src>=0 && src<4096) ? xb[i*4096+src] : 0.0f;
    }
    #pragma unroll
    for(int oo=0;oo<8;++oo){
      const float* wr = w + (size_t)(og*8+oo)*60 + i*5;
      #pragma unroll
      for(int k=0;k<5;++k) acc[oo] = fmaf(wr[k], xv[k], acc[oo]);
    }
  }
  #pragma unroll
  for(int oo=0;oo<8;++oo){
    int o = og*8+oo;
    float y = geluf(acc[oo]);
    float sc = g[o]*rsqrtf(v[o]+1e-5f);
    y = (y-m[o])*sc + bb[o];
    out[(size_t)b*192*2048 + (size_t)o*2048 + t] = y;
  }
}

// ---------------- transpose-cast h1 [b][i][t] fp32 -> T1 [b*2048+t][192] bf16 ----------------
__global__ void xpose1_k(const float* __restrict__ h1, unsigned short* __restrict__ T1){
  __shared__ float tile[32][33];
  int t0 = blockIdx.x*32, i0 = blockIdx.y*32, b = blockIdx.z;
  int c = threadIdx.x & 31, r4 = threadIdx.x >> 5;
  const float* src = h1 + (size_t)b*393216;
  #pragma unroll
  for(int i=0;i<4;++i){ int r = r4 + i*8; tile[r][c] = src[(size_t)(i0+r)*2048 + t0 + c]; }
  __syncthreads();
  unsigned short* dst = T1 + (size_t)b*2048*192;
  #pragma unroll
  for(int i=0;i<4;++i){ int r = r4 + i*8;
    dst[(size_t)(t0+r)*192 + i0 + c] = f2bf(tile[c][r]);
  }
}

// ---------------- fused weight prep: in_proj W bf16 + w2/w3 reorder bf16 ----------------
__global__ void wprep_k(const float* __restrict__ ipw, const float* __restrict__ w2,
                        const float* __restrict__ w3, unsigned short* __restrict__ Wb,
                        unsigned short* __restrict__ w2r, unsigned short* __restrict__ w3r){
  int gid = blockIdx.x*256 + threadIdx.x;   // 3,661,824 total
  if(gid < 2555904){
    Wb[gid] = f2bf(ipw[gid]);
  } else if(gid < 2555904+221184){
    int g2 = gid - 2555904;
    int o = g2 / 576, rem = g2 - o*576, k = rem / 192, i = rem - k*192;
    w2r[g2] = f2bf(w2[(size_t)o*576 + i*3 + k]);
  } else if(gid < 2555904+221184+884736){
    int g3 = gid - 2555904 - 221184;
    int o = g3 / 1152, rem = g3 - o*1152, k = rem / 384, i = rem - k*384;
    w3r[g3] = f2bf(w3[(size_t)o*1152 + i*3 + k]);
  }
}

// ---------------- conv2 as MFMA GEMM: M=8192, N=384, K=576 (3 taps x 192 ch, stride 2) ----------------
__global__ __launch_bounds__(256) void conv2_mfma(const unsigned short* __restrict__ A,
                                                  const unsigned short* __restrict__ W,
                                                  const float* __restrict__ bias,
                                                  const float* __restrict__ g, const float* __restrict__ bb,
                                                  const float* __restrict__ bm, const float* __restrict__ bv,
                                                  unsigned short* __restrict__ outb){
  __shared__ unsigned short As[4096], Bs[4096];
  const int tid = threadIdx.x;
  const int lane = tid & 63, wave = tid >> 6;
  const int wm = wave & 1, wn = wave >> 1;
  const int m0 = blockIdx.y*128, n0 = blockIdx.x*128;
  const int bidx = m0 >> 10, tloc = m0 & 1023;
  f32x4 acc[4][4];
  #pragma unroll
  for(int i=0;i<4;++i)
    #pragma unroll
    for(int j=0;j<4;++j) acc[i][j] = (f32x4){0.f,0.f,0.f,0.f};
  const int u0 = tid, u1 = tid + 256;
  const int r0 = u0>>2, kl0 = (u0&3) ^ ((r0>>1)&3);
  const int r1 = u1>>2, kl1 = (u1&3) ^ ((r1>>1)&3);
  const int kg = lane>>4, ml = lane&15;
  const short8 z8 = {0,0,0,0,0,0,0,0};
  for(int kb=0; kb<3; ++kb){
    int ta = 2*(tloc + r0) + kb - 1;
    int tb = 2*(tloc + r1) + kb - 1;
    bool va = (ta>=0) && (ta<2048);
    bool vb = (tb>=0) && (tb<2048);
    const unsigned short* pa = A + ((size_t)bidx*2048 + ta)*192;
    const unsigned short* pb = A + ((size_t)bidx*2048 + tb)*192;
    for(int c0=0; c0<192; c0+=32){
      int k0 = kb*192 + c0;
      short8 a0 = va ? *reinterpret_cast<const short8*>(pa + c0 + kl0*8) : z8;
      short8 a1 = vb ? *reinterpret_cast<const short8*>(pb + c0 + kl1*8) : z8;
      short8 b0 = *reinterpret_cast<const short8*>(W + (size_t)(n0+r0)*576 + k0 + kl0*8);
      short8 b1 = *reinterpret_cast<const short8*>(W + (size_t)(n0+r1)*576 + k0 + kl1*8);
      __syncthreads();
      *reinterpret_cast<short8*>(As + u0*8) = a0;
      *reinterpret_cast<short8*>(As + u1*8) = a1;
      *reinterpret_cast<short8*>(Bs + u0*8) = b0;
      *reinterpret_cast<short8*>(Bs + u1*8) = b1;
      __syncthreads();
      short8 af[4], bfr[4];
      #pragma unroll
      for(int f=0;f<4;++f){
        int row = wm*64 + f*16 + ml;
        int un  = row*4 + (kg ^ ((row>>1)&3));
        af[f] = *reinterpret_cast<const short8*>(As + un*8);
        int rowb = wn*64 + f*16 + ml;
        int ub   = rowb*4 + (kg ^ ((rowb>>1)&3));
        bfr[f] = *reinterpret_cast<const short8*>(Bs + ub*8);
      }
      #pragma unroll
      for(int i=0;i<4;++i)
        #pragma unroll
        for(int j=0;j<4;++j)
          acc[i][j] = __builtin_amdgcn_mfma_f32_16x16x32_bf16(af[i], bfr[j], acc[i][j], 0, 0, 0);
    }
  }
  #pragma unroll
  for(int i=0;i<4;++i){
    int rb = m0 + wm*64 + i*16 + kg*4;
    #pragma unroll
    for(int j=0;j<4;++j){
      int col = n0 + wn*64 + j*16 + ml;
      float sc = g[col]*rsqrtf(bv[col]+1e-5f);
      float mm = bm[col], bbv = bb[col], bi = bias[col];
      #pragma unroll
      for(int r=0;r<4;++r){
        float yv = geluf(acc[i][j][r] + bi);
        yv = (yv - mm)*sc + bbv;
        outb[(size_t)(rb+r)*384 + col] = f2bf(yv);
      }
    }
  }
}

// ---------------- conv3 as MFMA GEMM: M=8192, N=768, K=1152 (3 taps x 384 ch, stride 1) ----------------
__global__ __launch_bounds__(256) void conv3_mfma(const unsigned short* __restrict__ A,
                                                  const unsigned short* __restrict__ W,
                                                  const float* __restrict__ bias,
                                                  const float* __restrict__ g, const float* __restrict__ bb,
                                                  const float* __restrict__ bm, const float* __restrict__ bv,
                                                  unsigned short* __restrict__ outb,
                                                  float* __restrict__ outf){
  __shared__ unsigned short As[4096], Bs[4096];
  const int tid = threadIdx.x;
  const int lane = tid & 63, wave = tid >> 6;
  const int wm = wave & 1, wn = wave >> 1;
  const int m0 = blockIdx.y*128, n0 = blockIdx.x*128;
  const int bidx = m0 >> 10, tloc = m0 & 1023;
  f32x4 acc[4][4];
  #pragma unroll
  for(int i=0;i<4;++i)
    #pragma unroll
    for(int j=0;j<4;++j) acc[i][j] = (f32x4){0.f,0.f,0.f,0.f};
  const int u0 = tid, u1 = tid + 256;
  const int r0 = u0>>2, kl0 = (u0&3) ^ ((r0>>1)&3);
  const int r1 = u1>>2, kl1 = (u1&3) ^ ((r1>>1)&3);
  const int kg = lane>>4, ml = lane&15;
  const short8 z8 = {0,0,0,0,0,0,0,0};
  for(int kb=0; kb<3; ++kb){
    int ta = tloc + r0 + kb - 1;
    int tb = tloc + r1 + kb - 1;
    bool va = (ta>=0) && (ta<1024);
    bool vb = (tb>=0) && (tb<1024);
    const unsigned short* pa = A + ((size_t)bidx*1024 + ta)*384;
    const unsigned short* pb = A + ((size_t)bidx*1024 + tb)*384;
    for(int c0=0; c0<384; c0+=32){
      int k0 = kb*384 + c0;
      short8 a0 = va ? *reinterpret_cast<const short8*>(pa + c0 + kl0*8) : z8;
      short8 a1 = vb ? *reinterpret_cast<const short8*>(pb + c0 + kl1*8) : z8;
      short8 b0 = *reinterpret_cast<const short8*>(W + (size_t)(n0+r0)*1152 + k0 + kl0*8);
      short8 b1 = *reinterpret_cast<const short8*>(W + (size_t)(n0+r1)*1152 + k0 + kl1*8);
      __syncthreads();
      *reinterpret_cast<short8*>(As + u0*8) = a0;
      *reinterpret_cast<short8*>(As + u1*8) = a1;
      *reinterpret_cast<short8*>(Bs + u0*8) = b0;
      *reinterpret_cast<short8*>(Bs + u1*8) = b1;
      __syncthreads();
      short8 af[4], bfr[4];
      #pragma unroll
      for(int f=0;f<4;++f){
        int row = wm*64 + f*16 + ml;
        int un  = row*4 + (kg ^ ((row>>1)&3));
        af[f] = *reinterpret_cast<const short8*>(As + un*8);
        int rowb = wn*64 + f*16 + ml;
        int ub   = rowb*4 + (kg ^ ((rowb>>1)&3));
        bfr[f] = *reinterpret_cast<const short8*>(Bs + ub*8);
      }
      #pragma unroll
      for(int i=0;i<4;++i)
        #pragma unroll
        for(int j=0;j<4;++j)
          acc[i][j] = __builtin_amdgcn_mfma_f32_16x16x32_bf16(af[i], bfr[j], acc[i][j], 0, 0, 0);
    }
  }
  #pragma unroll
  for(int i=0;i<4;++i){
    int rb = m0 + wm*64 + i*16 + kg*4;
    #pragma unroll
    for(int j=0;j<4;++j){
      int col = n0 + wn*64 + j*16 + ml;
      float sc = g[col]*rsqrtf(bv[col]+1e-5f);
      float mm = bm[col], bbv = bb[col], bi = bias[col];
      #pragma unroll
      for(int r=0;r<4;++r){
        float yv = geluf(acc[i][j][r] + bi);
        yv = (yv - mm)*sc + bbv;
        outb[(size_t)(rb+r)*768 + col] = f2bf(yv);
        outf[(size_t)(rb+r)*768 + col] = yv;
      }
    }
  }
}

// ---------------- in_proj MFMA (reg-staged, r5-proven): M=8192 N=3328 K=768 ----------------
// Output split: cols 0..1535 -> Z [8192][1536], cols 1536..3327 -> XB [8192][1792].
__global__ __launch_bounds__(256) void inproj_mfma(const unsigned short* __restrict__ A,
                                                   const unsigned short* __restrict__ B,
                                                   float* __restrict__ Z, float* __restrict__ XB){
  __shared__ unsigned short As[4096], Bs[4096];
  const int tid = threadIdx.x;
  const int lane = tid & 63, wave = tid >> 6;
  const int wm = wave & 1, wn = wave >> 1;
  const int m0 = blockIdx.y*128, n0 = blockIdx.x*128;
  f32x4 acc[4][4];
  #pragma unroll
  for(int i=0;i<4;++i)
    #pragma unroll
    for(int j=0;j<4;++j) acc[i][j] = (f32x4){0.f,0.f,0.f,0.f};
  const int u0 = tid, u1 = tid + 256;
  const int r0 = u0>>2, kl0 = (u0&3) ^ ((r0>>1)&3);
  const int r1 = u1>>2, kl1 = (u1&3) ^ ((r1>>1)&3);
  const int kg = lane>>4, ml = lane&15;
  for(int k0=0;k0<768;k0+=32){
    short8 a0 = *reinterpret_cast<const short8*>(A + (size_t)(m0+r0)*768 + k0 + kl0*8);
    short8 a1 = *reinterpret_cast<const short8*>(A + (size_t)(m0+r1)*768 + k0 + kl1*8);
    short8 b0 = *reinterpret_cast<const short8*>(B + (size_t)(n0+r0)*768 + k0 + kl0*8);
    short8 b1 = *reinterpret_cast<const short8*>(B + (size_t)(n0+r1)*768 + k0 + kl1*8);
    __syncthreads();
    *reinterpret_cast<short8*>(As + u0*8) = a0;
    *reinterpret_cast<short8*>(As + u1*8) = a1;
    *reinterpret_cast<short8*>(Bs + u0*8) = b0;
    *reinterpret_cast<short8*>(Bs + u1*8) = b1;
    __syncthreads();
    short8 af[4], bfr[4];
    #pragma unroll
    for(int f=0;f<4;++f){
      int row = wm*64 + f*16 + ml;
      int un  = row*4 + (kg ^ ((row>>1)&3));
      af[f] = *reinterpret_cast<const short8*>(As + un*8);
      int rowb = wn*64 + f*16 + ml;
      int ub   = rowb*4 + (kg ^ ((rowb>>1)&3));
      bfr[f] = *reinterpret_cast<const short8*>(Bs + ub*8);
    }
    #pragma unroll
    for(int i=0;i<4;++i)
      #pragma unroll
      for(int j=0;j<4;++j)
        acc[i][j] = __builtin_amdgcn_mfma_f32_16x16x32_bf16(af[i], bfr[j], acc[i][j], 0, 0, 0);
  }
  float* op; int cb; int stride;
  if(n0 < 1536){ op = Z;  cb = n0;        stride = 1536; }
  else         { op = XB; cb = n0 - 1536; stride = 1792; }
  #pragma unroll
  for(int i=0;i<4;++i){
    int rb = m0 + wm*64 + i*16 + kg*4;
    #pragma unroll
    for(int j=0;j<4;++j){
      int col = cb + wn*64 + j*16 + ml;
      #pragma unroll
      for(int r=0;r<4;++r)
        op[(size_t)(rb+r)*stride + col] = acc[i][j][r];
    }
  }
}

// ---------------- dt GEMM (fp32, row-major h3) + softplus + dA, fused ----------------
__global__ __launch_bounds__(256) void dtgemm2_k(const float* __restrict__ h3f, const float* __restrict__ W,
                                                 const float* __restrict__ dt_bias, const float* __restrict__ A_log,
                                                 float* __restrict__ dt, float* __restrict__ dA){
  __shared__ float Ws[12][768];
  __shared__ float Ah[12], Bh[12];
  int tid = threadIdx.x;
  for(int idx=tid; idx<9216; idx+=256){
    int hh = idx/768, k = idx - hh*768;
    Ws[hh][k] = W[(size_t)(3328+hh)*768 + k];
  }
  if(tid<12){ Ah[tid] = -expf(A_log[tid]); Bh[tid] = dt_bias[tid]; }
  __syncthreads();
  int wave = tid>>6, lane = tid&63;
  int m = blockIdx.x*4 + wave;
  const float* xr = h3f + (size_t)m*768;
  float xv[12];
  #pragma unroll
  for(int q=0;q<12;++q) xv[q] = xr[q*64+lane];
  float res[12];
  #pragma unroll
  for(int h=0;h<12;++h){
    float acc = 0.f;
    #pragma unroll
    for(int q=0;q<12;++q) acc = fmaf(xv[q], Ws[h][q*64+lane], acc);
    #pragma unroll
    for(int off=32;off;off>>=1) acc += __shfl_xor(acc, off);
    res[h] = acc;
  }
  if(lane==0){
    #pragma unroll
    for(int h=0;h<12;++h){
      float sp = softplusf(res[h] + Bh[h]);
      dt[(size_t)m*12+h] = sp;
      dA[(size_t)m*12+h] = expf(sp*Ah[h]);
    }
  }
}

// ---------------- depthwise causal conv k=4 + silu + split (float4, compact XB) ----------------
__global__ void dwconv_k(const float* __restrict__ XB, const float* __restrict__ cw,
                         const float* __restrict__ cb, float* __restrict__ xs,
                         float* __restrict__ Bo, float* __restrict__ Co){
  int gid = blockIdx.x*256 + threadIdx.x;   // 8192*448
  int c4 = gid % 448;
  int m = gid / 448;
  int t = m & 1023;
  int c = c4*4;
  float wA[4][4];
  #pragma unroll
  for(int i=0;i<4;++i)
    *reinterpret_cast<float4*>(wA[i]) = *reinterpret_cast<const float4*>(&cw[(c+i)*4]);
  float4 bi = *reinterpret_cast<const float4*>(&cb[c]);
  float av[4] = {bi.x, bi.y, bi.z, bi.w};
  #pragma unroll
  for(int j=0;j<4;++j){
    int tt = t - 3 + j;
    if(tt >= 0){
      float4 xv = *reinterpret_cast<const float4*>(&XB[(size_t)(m-3+j)*1792 + c]);
      av[0] = fmaf(wA[0][j], xv.x, av[0]);
      av[1] = fmaf(wA[1][j], xv.y, av[1]);
      av[2] = fmaf(wA[2][j], xv.z, av[2]);
      av[3] = fmaf(wA[3][j], xv.w, av[3]);
    }
  }
  float4 res = make_float4(siluf(av[0]), siluf(av[1]), siluf(av[2]), siluf(av[3]));
  if(c4 < 384)      *reinterpret_cast<float4*>(&xs[(size_t)m*1536 + c])        = res;
  else if(c4 < 416) *reinterpret_cast<float4*>(&Bo[(size_t)m*128 + (c-1536)])  = res;
  else              *reinterpret_cast<float4*>(&Co[(size_t)m*128 + (c-1664)])  = res;
}

// ---------------- per-chunk inclusive cumprod of dA ----------------
__global__ void cumda_k(const float* __restrict__ dA, float* __restrict__ cda){
  __shared__ float ld[1024];
  int bh = blockIdx.x; int b = bh/12, hh = bh - b*12;
  int tid = threadIdx.x;
  for(int i=tid;i<1024;i+=128) ld[i] = dA[((size_t)b*1024 + i)*12 + hh];
  __syncthreads();
  for(int c=0;c<8;++c){
    int base = c*128;
    for(int off=1;off<128;off<<=1){
      float v = ld[base+tid];
      if(tid>=off) v *= ld[base+tid-off];
      __syncthreads();
      ld[base+tid] = v;
      __syncthreads();
    }
  }
  for(int i=tid;i<1024;i+=128) cda[(size_t)bh*1024 + i] = ld[i];
}

// ---------------- SSM scan pass 1 (r5-proven 4p x 32n; ly removed, direct y-store) ----------------
#define SSTEP(E, BQE, CQE) \
  s[0][jj*4+E] = fmaf(s[0][jj*4+E], dav, c0*BQE); y0 = fmaf(s[0][jj*4+E], CQE, y0); \
  s[1][jj*4+E] = fmaf(s[1][jj*4+E], dav, c1*BQE); y1 = fmaf(s[1][jj*4+E], CQE, y1); \
  s[2][jj*4+E] = fmaf(s[2][jj*4+E], dav, c2*BQE); y2 = fmaf(s[2][jj*4+E], CQE, y2); \
  s[3][jj*4+E] = fmaf(s[3][jj*4+E], dav, c3*BQE); y3 = fmaf(s[3][jj*4+E], CQE, y3);

__global__ __launch_bounds__(128) void scan_chunk_k(float* __restrict__ xs,
    const float* __restrict__ Bm, const float* __restrict__ Cm,
    const float* __restrict__ dtb, const float* __restrict__ dAb,
    const float* __restrict__ Dv, float* __restrict__ sfin){
  const int c = blockIdx.x, h = blockIdx.y, b = blockIdx.z;
  const int tid = threadIdx.x;
  const int ng = tid & 3, pg = tid >> 2;   // p = pg*4+i, n = ng*32+...
  __shared__ float lx[16][128], lB[16][144], lC[16][144];
  __shared__ float ldt[16], lda_[16];
  float s[4][32];
  #pragma unroll
  for(int i=0;i<4;++i)
    #pragma unroll
    for(int j=0;j<32;++j) s[i][j]=0.f;
  const float Dh = Dv[h];
  const size_t mb = (size_t)b*1024 + (size_t)c*128;
  for(int t0=0;t0<128;t0+=16){
    for(int idx=tid; idx<2048; idx+=128){
      int tl = idx>>7, cc = idx&127;
      lx[tl][cc] = xs[(mb+t0+tl)*1536 + h*128 + cc];
      int slot = (cc>>5)*36 + (cc&31);
      lB[tl][slot] = Bm[(mb+t0+tl)*128 + cc];
      lC[tl][slot] = Cm[(mb+t0+tl)*128 + cc];
    }
    if(tid<16){
      ldt[tid]  = dtb[(mb+t0+tid)*12 + h];
      lda_[tid] = dAb[(mb+t0+tid)*12 + h];
    }
    __syncthreads();
    for(int tl=0; tl<16; ++tl){
      float dtv = ldt[tl], dav = lda_[tl];
      float4 xq = *reinterpret_cast<const float4*>(&lx[tl][pg*4]);
      float c0 = dtv*xq.x, c1 = dtv*xq.y, c2 = dtv*xq.z, c3 = dtv*xq.w;
      float y0=0.f,y1=0.f,y2=0.f,y3=0.f;
      #pragma unroll
      for(int jj=0;jj<8;++jj){
        float4 bq = *reinterpret_cast<const float4*>(&lB[tl][ng*36+jj*4]);
        float4 cq = *reinterpret_cast<const float4*>(&lC[tl][ng*36+jj*4]);
        SSTEP(0, bq.x, cq.x)
        SSTEP(1, bq.y, cq.y)
        SSTEP(2, bq.z, cq.z)
        SSTEP(3, bq.w, cq.w)
      }
      y0 += __shfl_xor(y0,1); y0 += __shfl_xor(y0,2);
      y1 += __shfl_xor(y1,1); y1 += __shfl_xor(y1,2);
      y2 += __shfl_xor(y2,1); y2 += __shfl_xor(y2,2);
      y3 += __shfl_xor(y3,1); y3 += __shfl_xor(y3,2);
      if(ng==0){
        // y + D*x straight to global (x original value from registers)
        float4 st = make_float4(y0 + Dh*xq.x, y1 + Dh*xq.y, y2 + Dh*xq.z, y3 + Dh*xq.w);
        *reinterpret_cast<float4*>(&xs[(mb+t0+tl)*1536 + h*128 + pg*4]) = st;
      }
    }
    __syncthreads();
  }
  // store local final state, [n][p] layout
  float* dst = sfin + ((size_t)(b*12+h)*8 + c)*16384;
  #pragma unroll
  for(int jj=0;jj<8;++jj)
    #pragma unroll
    for(int e=0;e<4;++e){
      int n = ng*32 + jj*4 + e;
      *reinterpret_cast<float4*>(&dst[(size_t)n*128 + pg*4]) =
        make_float4(s[0][jj*4+e], s[1][jj*4+e], s[2][jj*4+e], s[3][jj*4+e]);
    }
}

// ---------------- SSM scan pass 2: inter-chunk correction y += cumP * (C . S_init) ----------------
__global__ __launch_bounds__(256) void correct_k(const float* __restrict__ Cm,
    const float* __restrict__ cumdA, const float* __restrict__ sfin,
    float* __restrict__ ys){
  const int c = blockIdx.x + 1, h = blockIdx.y, b = blockIdx.z;
  const int tid = threadIdx.x;
  const size_t bh = (size_t)b*12 + h;
  __shared__ float Sl[16][128];
  __shared__ float Cl[16][132];
  __shared__ float cumP[128];
  __shared__ float coefs[8];
  if(tid==0){
    float cf = 1.f;
    for(int cp=c-1; cp>=0; --cp){
      coefs[cp] = cf;
      cf *= cumdA[bh*1024 + (size_t)cp*128 + 127];
    }
  }
  if(tid<128) cumP[tid] = cumdA[bh*1024 + (size_t)c*128 + tid];
  __syncthreads();
  const int tp = tid>>4, tt = tid&15;
  float acc[8][8];
  #pragma unroll
  for(int i=0;i<8;++i)
    #pragma unroll
    for(int j=0;j<8;++j) acc[i][j]=0.f;
  const size_t mb = (size_t)b*1024 + (size_t)c*128;
  for(int n0=0;n0<128;n0+=16){
    {
      int kk = tid>>4, po = tid&15;
      float4 v0 = {0,0,0,0}, v1 = {0,0,0,0};
      for(int cp=0; cp<c; ++cp){
        const float* sp = sfin + ((bh*8 + cp)*16384) + (size_t)(n0+kk)*128 + po*8;
        float4 a0 = *reinterpret_cast<const float4*>(sp);
        float4 a1 = *reinterpret_cast<const float4*>(sp+4);
        float cf = coefs[cp];
        v0.x = fmaf(cf,a0.x,v0.x); v0.y = fmaf(cf,a0.y,v0.y);
        v0.z = fmaf(cf,a0.z,v0.z); v0.w = fmaf(cf,a0.w,v0.w);
        v1.x = fmaf(cf,a1.x,v1.x); v1.y = fmaf(cf,a1.y,v1.y);
        v1.z = fmaf(cf,a1.z,v1.z); v1.w = fmaf(cf,a1.w,v1.w);
      }
      *reinterpret_cast<float4*>(&Sl[kk][po*8])   = v0;
      *reinterpret_cast<float4*>(&Sl[kk][po*8+4]) = v1;
    }
    #pragma unroll
    for(int e=0;e<8;++e){
      int idx = tid*8 + e; int tl = idx>>4, kk = idx&15;
      Cl[kk][tl] = Cm[(mb + tl)*128 + n0 + kk];
    }
    __syncthreads();
    #pragma unroll
    for(int kk=0;kk<16;++kk){
      float4 sa = *reinterpret_cast<const float4*>(&Sl[kk][tp*8]);
      float4 sb = *reinterpret_cast<const float4*>(&Sl[kk][tp*8+4]);
      float4 ca = *reinterpret_cast<const float4*>(&Cl[kk][tt*8]);
      float4 cb = *reinterpret_cast<const float4*>(&Cl[kk][tt*8+4]);
      float sv[8] = {sa.x,sa.y,sa.z,sa.w,sb.x,sb.y,sb.z,sb.w};
      float cv[8] = {ca.x,ca.y,ca.z,ca.w,cb.x,cb.y,cb.z,cb.w};
      #pragma unroll
      for(int i=0;i<8;++i)
        #pragma unroll
        for(int j=0;j<8;++j) acc[i][j] = fmaf(sv[i], cv[j], acc[i][j]);
    }
    __syncthreads();
  }
  #pragma unroll
  for(int j=0;j<8;++j){
    int tl = tt*8 + j;
    float cp = cumP[tl];
    float* yp = ys + (mb + tl)*1536 + h*128 + tp*8;
    float4 y0 = *reinterpret_cast<float4*>(yp);
    float4 y1 = *reinterpret_cast<float4*>(yp+4);
    y0.x += cp*acc[0][j]; y0.y += cp*acc[1][j]; y0.z += cp*acc[2][j]; y0.w += cp*acc[3][j];
    y1.x += cp*acc[4][j]; y1.y += cp*acc[5][j]; y1.z += cp*acc[6][j]; y1.w += cp*acc[7][j];
    *reinterpret_cast<float4*>(yp)   = y0;
    *reinterpret_cast<float4*>(yp+4) = y1;
  }
}

// ---------------- gating: y*silu(z), RMSNorm, write scaled rows (no atomics) ----------------
__global__ void gate_k(const float* __restrict__ ys, const float* __restrict__ Z,
                       const float* __restrict__ nw, float* __restrict__ ysc){
  int m = blockIdx.x;
  int tid = threadIdx.x;
  float gvals[6];
  float ss = 0.0f;
  #pragma unroll
  for(int r=0;r<6;++r){
    int c = r*256 + tid;
    float yv = ys[(size_t)m*1536 + c];
    float zv = Z[(size_t)m*1536 + c];
    float gv = yv * siluf(zv);
    gvals[r] = gv;
    ss = fmaf(gv, gv, ss);
  }
  #pragma unroll
  for(int off=32;off;off>>=1) ss += __shfl_xor(ss, off);
  __shared__ float red[4];
  if((tid&63)==0) red[tid>>6] = ss;
  __syncthreads();
  float tot = red[0]+red[1]+red[2]+red[3];
  float scale = rsqrtf(tot*(1.0f/1536.0f) + 1e-5f);
  #pragma unroll
  for(int r=0;r<6;++r){
    int c = r*256 + tid;
    ysc[(size_t)m*1536 + c] = gvals[r]*scale*nw[c];
  }
}

// ---------------- ysum: partial column sums over 128-row chunks ----------------
__global__ void ysum_k(const float* __restrict__ ysc, float* __restrict__ part){
  int bid = blockIdx.x;                 // 384 = 8 b x 6 cs x 8 tc
  int bb = bid / 48, rem = bid % 48;
  int cs = rem / 8, tc = rem % 8;
  int col = cs*256 + threadIdx.x;
  const float* base = ysc + ((size_t)bb*1024 + tc*128)*1536 + col;
  float s = 0.f;
  for(int r=0;r<128;++r) s += base[(size_t)r*1536];
  part[((size_t)(bb*6+cs)*8 + tc)*256 + threadIdx.x] = s;
}

// ---------------- final mean over t ----------------
__global__ void ybm2_k(const float* __restrict__ part, float* __restrict__ ybm){
  int idx = blockIdx.x*256 + threadIdx.x;   // 12288
  int bb = idx / 1536, cc = idx % 1536;
  int cs = cc / 256, ci = cc % 256;
  float s = 0.f;
  #pragma unroll
  for(int tc=0;tc<8;++tc) s += part[((size_t)(bb*6+cs)*8 + tc)*256 + ci];
  ybm[idx] = s * (1.0f/1024.0f);
}

__global__ void rep_k(const float* __restrict__ ybm, const float* __restrict__ W,
                      float* __restrict__ rep){
  int wid  = (blockIdx.x<<2) + (threadIdx.x>>6);
  int lane = threadIdx.x & 63;
  int b = wid / 768, o = wid % 768;
  const float* xr = ybm + (size_t)b*1536;
  const float* wr = W + (size_t)o*1536;
  float acc = 0.0f;
  for(int c=lane;c<1536;c+=64) acc = fmaf(xr[c], wr[c], acc);
  #pragma unroll
  for(int off=32;off;off>>=1) acc += __shfl_xor(acc, off);
  if(lane==0) rep[wid] = acc;
}

__global__ void fc1_k(const float* __restrict__ rep, const float* __restrict__ W,
                      const float* __restrict__ bias, const float* __restrict__ g,
                      const float* __restrict__ bb, const float* __restrict__ m,
                      const float* __restrict__ v, float* __restrict__ out){
  int wid  = (blockIdx.x<<2) + (threadIdx.x>>6);
  int lane = threadIdx.x & 63;
  int b = wid >> 10, o = wid & 1023;
  const float* xr = rep + (size_t)b*768;
  const float* wr = W + (size_t)o*768;
  float acc = 0.0f;
  for(int c=lane;c<768;c+=64) acc = fmaf(xr[c], wr[c], acc);
  #pragma unroll
  for(int off=32;off;off>>=1) acc += __shfl_xor(acc, off);
  if(lane==0){
    float val = acc + bias[o];
    float sc = g[o]*rsqrtf(v[o]+1e-5f);
    val = (val - m[o])*sc + bb[o];
    out[wid] = fmaxf(val, 0.0f);
  }
}

__global__ void fc2_k(const float* __restrict__ h1, const float* __restrict__ W,
                      const float* __restrict__ bias, float* __restrict__ out){
  int wid  = (blockIdx.x<<2) + (threadIdx.x>>6);
  int lane = threadIdx.x & 63;
  int b = wid / 27, o = wid % 27;
  const float* xr = h1 + (size_t)b*1024;
  const float* wr = W + (size_t)o*1024;
  float acc = 0.0f;
  for(int c=lane;c<1024;c+=64) acc = fmaf(xr[c], wr[c], acc);
  #pragma unroll
  for(int off=32;off;off>>=1) acc += __shfl_xor(acc, off);
  if(lane==0) out[wid] = acc + bias[o];
}

// ---------------- workspace layout (float offsets) ----------------
// Footprint: 54,945,792 floats (proven cap).
#define OFF_H1     0u           // 3,145,728 fp32 [conv1 -> xpose1]
#define OFF_T1     3145728u     // ushort x 3,145,728 [xpose1 -> conv2]
#define OFF_T2     4718592u     // ushort x 3,145,728 [conv2 -> conv3]
#define OFF_H3T    6291456u     // ushort x 6,291,456 [conv3 -> inproj]
#define OFF_WB     9437184u     // ushort x 2,555,904 [wprep -> inproj]
#define OFF_W2R    10715136u    // ushort x 221,184
#define OFF_W3R    10825728u    // ushort x 884,736 ; early region ends 11,268,096
#define OFF_Z      12582912u    // 12,582,912 fp32 [inproj -> gate]
#define OFF_XB     25165824u    // 14,680,064 fp32 [inproj -> dwconv] ends 39,845,888
#define OFF_XS     39944192u    // 12,582,912 (h3f first, then xs/ys)
#define OFF_H3F    39944192u    // 6,291,456 fp32 [conv3 -> dtgemm2, before dwconv]
#define OFF_B      52527104u    // 1,048,576
#define OFF_C      53575680u    // 1,048,576
#define OFF_DT     54624256u    // 98,304
#define OFF_DA     54722560u    // 98,304
#define OFF_SLOT98K 54820864u   // 98,304: cda (cumda->correct) then ysum partials
#define OFF_YBM    54919168u    // 12,288
#define OFF_REP    54931456u    // 6,144
#define OFF_FC1    54937600u    // 8,192 ; end = 54,945,792
#define OFF_SFIN   0u           // 12,582,912 [scan -> correct], then ysc [gate -> ysum]

extern "C" void kernel_launch(void* const* d_in, const int* in_sizes, int n_in,
                              void* d_out, int out_size, void* d_ws, size_t ws_size,
                              hipStream_t stream){
  const float* x       = (const float*)d_in[0];
  const float* w1      = (const float*)d_in[1];
  const float* b1      = (const float*)d_in[2];
  const float* bn1g    = (const float*)d_in[3];
  const float* bn1b    = (const float*)d_in[4];
  const float* bn1m    = (const float*)d_in[5];
  const float* bn1v    = (const float*)d_in[6];
  const float* w2      = (const float*)d_in[7];
  const float* b2      = (const float*)d_in[8];
  const float* bn2g    = (const float*)d_in[9];
  const float* bn2b    = (const float*)d_in[10];
  const float* bn2m    = (const float*)d_in[11];
  const float* bn2v    = (const float*)d_in[12];
  const float* w3      = (const float*)d_in[13];
  const float* b3      = (const float*)d_in[14];
  const float* bn3g    = (const float*)d_in[15];
  const float* bn3b    = (const float*)d_in[16];
  const float* bn3m    = (const float*)d_in[17];
  const float* bn3v    = (const float*)d_in[18];
  const float* ipw     = (const float*)d_in[19];
  const float* convw   = (const float*)d_in[20];
  const float* convb   = (const float*)d_in[21];
  const float* dtbias  = (const float*)d_in[22];
  const float* Alog    = (const float*)d_in[23];
  const float* Dvec    = (const float*)d_in[24];
  const float* normw   = (const float*)d_in[25];
  const float* opw     = (const float*)d_in[26];
  const float* fc1w    = (const float*)d_in[27];
  const float* fc1b    = (const float*)d_in[28];
  const float* bncg    = (const float*)d_in[29];
  const float* bncb    = (const float*)d_in[30];
  const float* bncm    = (const float*)d_in[31];
  const float* bncv    = (const float*)d_in[32];
  const float* fc2w    = (const float*)d_in[33];
  const float* fc2b    = (const float*)d_in[34];

  float* ws   = (float*)d_ws;
  float* h1   = ws + OFF_H1;
  unsigned short* T1  = (unsigned short*)(ws + OFF_T1);
  unsigned short* T2  = (unsigned short*)(ws + OFF_T2);
  unsigned short* h3t = (unsigned short*)(ws + OFF_H3T);
  unsigned short* Wb  = (unsigned short*)(ws + OFF_WB);
  unsigned short* w2r = (unsigned short*)(ws + OFF_W2R);
  unsigned short* w3r = (unsigned short*)(ws + OFF_W3R);
  float* Zb   = ws + OFF_Z;
  float* XBb  = ws + OFF_XB;
  float* xsb  = ws + OFF_XS;
  float* h3f  = ws + OFF_H3F;
  float* Bb   = ws + OFF_B;
  float* Cb   = ws + OFF_C;
  float* dtb  = ws + OFF_DT;
  float* dAb  = ws + OFF_DA;
  float* slot = ws + OFF_SLOT98K;
  float* ybm  = ws + OFF_YBM;
  float* rep  = ws + OFF_REP;
  float* f1b  = ws + OFF_FC1;
  float* sfin = ws + OFF_SFIN;
  float* ysc  = ws + OFF_SFIN;
  float* outp = (float*)d_out;

  conv1_k<<<dim3(8,24,8),  256, 0, stream>>>(x, w1, b1, bn1g, bn1b, bn1m, bn1v, h1);
  xpose1_k<<<dim3(64,6,8), 256, 0, stream>>>(h1, T1);
  wprep_k<<<14304, 256, 0, stream>>>(ipw, w2, w3, Wb, w2r, w3r);
  conv2_mfma<<<dim3(3,64), 256, 0, stream>>>(T1, w2r, b2, bn2g, bn2b, bn2m, bn2v, T2);
  conv3_mfma<<<dim3(6,64), 256, 0, stream>>>(T2, w3r, b3, bn3g, bn3b, bn3m, bn3v, h3t, h3f);
  dtgemm2_k<<<2048, 256, 0, stream>>>(h3f, ipw, dtbias, Alog, dtb, dAb);
  inproj_mfma<<<dim3(26,64), 256, 0, stream>>>(h3t, Wb, Zb, XBb);
  dwconv_k<<<14336, 256, 0, stream>>>(XBb, convw, convb, xsb, Bb, Cb);
  cumda_k<<<96, 128, 0, stream>>>(dAb, slot);                        // cda = slot
  scan_chunk_k<<<dim3(8,12,8), 128, 0, stream>>>(xsb, Bb, Cb, dtb, dAb, Dvec, sfin);
  correct_k<<<dim3(7,12,8), 256, 0, stream>>>(Cb, slot, sfin, xsb);  // reads cda
  gate_k<<<8192, 256, 0, stream>>>(xsb, Zb, normw, ysc);             // no atomics
  ysum_k<<<384, 256, 0, stream>>>(ysc, slot);                        // partials -> slot
  ybm2_k<<<48, 256, 0, stream>>>(slot, ybm);
  rep_k<<<1536, 256, 0, stream>>>(ybm, opw, rep);
  fc1_k<<<2048, 256, 0, stream>>>(rep, fc1w, fc1b, bncg, bncb, bncm, bncv, f1b);
  fc2_k<<<54, 256, 0, stream>>>(f1b, fc2w, fc2b, outp);
}

// Round 9
// 751.058 us; speedup vs baseline: 1.1433x; 1.1433x over previous
//
#include <hip/hip_runtime.h>
#include <math.h>

#define DEV __device__ __forceinline__

DEV float geluf(float x){ return 0.5f*x*(1.0f+erff(x*0.7071067811865476f)); }
DEV float siluf(float x){ return x/(1.0f+expf(-x)); }
DEV float softplusf(float x){ return fmaxf(x,0.0f)+log1pf(expf(-fabsf(x))); }
DEV unsigned short f2bf(float f){
  unsigned int u = __float_as_uint(f);
  unsigned int r = (u + 0x7fffu + ((u>>16)&1u)) >> 16;
  return (unsigned short)r;
}

typedef __attribute__((ext_vector_type(8))) short short8;
typedef __attribute__((ext_vector_type(4))) float f32x4;

// ---------------- conv1: (8,12,4096) -> (8,192,2048), k=5 s=2 p=2, gelu+bn ----------------
__global__ void conv1_k(const float* __restrict__ x, const float* __restrict__ w,
                        const float* __restrict__ bias,
                        const float* __restrict__ g, const float* __restrict__ bb,
                        const float* __restrict__ m, const float* __restrict__ v,
                        float* __restrict__ out){
  int t  = blockIdx.x*256 + threadIdx.x;
  int og = blockIdx.y;
  int b  = blockIdx.z;
  const float* xb = x + (size_t)b*12*4096;
  float acc[8];
  #pragma unroll
  for(int oo=0;oo<8;++oo) acc[oo] = bias[og*8+oo];
  for(int i=0;i<12;++i){
    float xv[5];
    #pragma unroll
    for(int k=0;k<5;++k){
      int src = 2*t + k - 2;
      xv[k] = (src>=0 && src<4096) ? xb[i*4096+src] : 0.0f;
    }
    #pragma unroll
    for(int oo=0;oo<8;++oo){
      const float* wr = w + (size_t)(og*8+oo)*60 + i*5;
      #pragma unroll
      for(int k=0;k<5;++k) acc[oo] = fmaf(wr[k], xv[k], acc[oo]);
    }
  }
  #pragma unroll
  for(int oo=0;oo<8;++oo){
    int o = og*8+oo;
    float y = geluf(acc[oo]);
    float sc = g[o]*rsqrtf(v[o]+1e-5f);
    y = (y-m[o])*sc + bb[o];
    out[(size_t)b*192*2048 + (size_t)o*2048 + t] = y;
  }
}

// ---------------- transpose-cast h1 [b][i][t] fp32 -> T1 [b*2048+t][192] bf16 ----------------
__global__ void xpose1_k(const float* __restrict__ h1, unsigned short* __restrict__ T1){
  __shared__ float tile[32][33];
  int t0 = blockIdx.x*32, i0 = blockIdx.y*32, b = blockIdx.z;
  int c = threadIdx.x & 31, r4 = threadIdx.x >> 5;
  const float* src = h1 + (size_t)b*393216;
  #pragma unroll
  for(int i=0;i<4;++i){ int r = r4 + i*8; tile[r][c] = src[(size_t)(i0+r)*2048 + t0 + c]; }
  __syncthreads();
  unsigned short* dst = T1 + (size_t)b*2048*192;
  #pragma unroll
  for(int i=0;i<4;++i){ int r = r4 + i*8;
    dst[(size_t)(t0+r)*192 + i0 + c] = f2bf(tile[c][r]);
  }
}

// ---------------- fused weight prep: in_proj W bf16 + w2/w3 reorder bf16 ----------------
__global__ void wprep_k(const float* __restrict__ ipw, const float* __restrict__ w2,
                        const float* __restrict__ w3, unsigned short* __restrict__ Wb,
                        unsigned short* __restrict__ w2r, unsigned short* __restrict__ w3r){
  int gid = blockIdx.x*256 + threadIdx.x;   // 3,661,824 total
  if(gid < 2555904){
    Wb[gid] = f2bf(ipw[gid]);
  } else if(gid < 2555904+221184){
    int g2 = gid - 2555904;
    int o = g2 / 576, rem = g2 - o*576, k = rem / 192, i = rem - k*192;
    w2r[g2] = f2bf(w2[(size_t)o*576 + i*3 + k]);
  } else if(gid < 2555904+221184+884736){
    int g3 = gid - 2555904 - 221184;
    int o = g3 / 1152, rem = g3 - o*1152, k = rem / 384, i = rem - k*384;
    w3r[g3] = f2bf(w3[(size_t)o*1152 + i*3 + k]);
  }
}

// ---------------- conv2 as MFMA GEMM: M=8192, N=384, K=576 (3 taps x 192 ch, stride 2) ----------------
__global__ __launch_bounds__(256) void conv2_mfma(const unsigned short* __restrict__ A,
                                                  const unsigned short* __restrict__ W,
                                                  const float* __restrict__ bias,
                                                  const float* __restrict__ g, const float* __restrict__ bb,
                                                  const float* __restrict__ bm, const float* __restrict__ bv,
                                                  unsigned short* __restrict__ outb){
  __shared__ unsigned short As[4096], Bs[4096];
  const int tid = threadIdx.x;
  const int lane = tid & 63, wave = tid >> 6;
  const int wm = wave & 1, wn = wave >> 1;
  const int m0 = blockIdx.y*128, n0 = blockIdx.x*128;
  const int bidx = m0 >> 10, tloc = m0 & 1023;
  f32x4 acc[4][4];
  #pragma unroll
  for(int i=0;i<4;++i)
    #pragma unroll
    for(int j=0;j<4;++j) acc[i][j] = (f32x4){0.f,0.f,0.f,0.f};
  const int u0 = tid, u1 = tid + 256;
  const int r0 = u0>>2, kl0 = (u0&3) ^ ((r0>>1)&3);
  const int r1 = u1>>2, kl1 = (u1&3) ^ ((r1>>1)&3);
  const int kg = lane>>4, ml = lane&15;
  const short8 z8 = {0,0,0,0,0,0,0,0};
  for(int kb=0; kb<3; ++kb){
    int ta = 2*(tloc + r0) + kb - 1;
    int tb = 2*(tloc + r1) + kb - 1;
    bool va = (ta>=0) && (ta<2048);
    bool vb = (tb>=0) && (tb<2048);
    const unsigned short* pa = A + ((size_t)bidx*2048 + ta)*192;
    const unsigned short* pb = A + ((size_t)bidx*2048 + tb)*192;
    for(int c0=0; c0<192; c0+=32){
      int k0 = kb*192 + c0;
      short8 a0 = va ? *reinterpret_cast<const short8*>(pa + c0 + kl0*8) : z8;
      short8 a1 = vb ? *reinterpret_cast<const short8*>(pb + c0 + kl1*8) : z8;
      short8 b0 = *reinterpret_cast<const short8*>(W + (size_t)(n0+r0)*576 + k0 + kl0*8);
      short8 b1 = *reinterpret_cast<const short8*>(W + (size_t)(n0+r1)*576 + k0 + kl1*8);
      __syncthreads();
      *reinterpret_cast<short8*>(As + u0*8) = a0;
      *reinterpret_cast<short8*>(As + u1*8) = a1;
      *reinterpret_cast<short8*>(Bs + u0*8) = b0;
      *reinterpret_cast<short8*>(Bs + u1*8) = b1;
      __syncthreads();
      short8 af[4], bfr[4];
      #pragma unroll
      for(int f=0;f<4;++f){
        int row = wm*64 + f*16 + ml;
        int un  = row*4 + (kg ^ ((row>>1)&3));
        af[f] = *reinterpret_cast<const short8*>(As + un*8);
        int rowb = wn*64 + f*16 + ml;
        int ub   = rowb*4 + (kg ^ ((rowb>>1)&3));
        bfr[f] = *reinterpret_cast<const short8*>(Bs + ub*8);
      }
      #pragma unroll
      for(int i=0;i<4;++i)
        #pragma unroll
        for(int j=0;j<4;++j)
          acc[i][j] = __builtin_amdgcn_mfma_f32_16x16x32_bf16(af[i], bfr[j], acc[i][j], 0, 0, 0);
    }
  }
  #pragma unroll
  for(int i=0;i<4;++i){
    int rb = m0 + wm*64 + i*16 + kg*4;
    #pragma unroll
    for(int j=0;j<4;++j){
      int col = n0 + wn*64 + j*16 + ml;
      float sc = g[col]*rsqrtf(bv[col]+1e-5f);
      float mm = bm[col], bbv = bb[col], bi = bias[col];
      #pragma unroll
      for(int r=0;r<4;++r){
        float yv = geluf(acc[i][j][r] + bi);
        yv = (yv - mm)*sc + bbv;
        outb[(size_t)(rb+r)*384 + col] = f2bf(yv);
      }
    }
  }
}

// ---------------- conv3 as MFMA GEMM: M=8192, N=768, K=1152 (3 taps x 384 ch, stride 1) ----------------
__global__ __launch_bounds__(256) void conv3_mfma(const unsigned short* __restrict__ A,
                                                  const unsigned short* __restrict__ W,
                                                  const float* __restrict__ bias,
                                                  const float* __restrict__ g, const float* __restrict__ bb,
                                                  const float* __restrict__ bm, const float* __restrict__ bv,
                                                  unsigned short* __restrict__ outb,
                                                  float* __restrict__ outf){
  __shared__ unsigned short As[4096], Bs[4096];
  const int tid = threadIdx.x;
  const int lane = tid & 63, wave = tid >> 6;
  const int wm = wave & 1, wn = wave >> 1;
  const int m0 = blockIdx.y*128, n0 = blockIdx.x*128;
  const int bidx = m0 >> 10, tloc = m0 & 1023;
  f32x4 acc[4][4];
  #pragma unroll
  for(int i=0;i<4;++i)
    #pragma unroll
    for(int j=0;j<4;++j) acc[i][j] = (f32x4){0.f,0.f,0.f,0.f};
  const int u0 = tid, u1 = tid + 256;
  const int r0 = u0>>2, kl0 = (u0&3) ^ ((r0>>1)&3);
  const int r1 = u1>>2, kl1 = (u1&3) ^ ((r1>>1)&3);
  const int kg = lane>>4, ml = lane&15;
  const short8 z8 = {0,0,0,0,0,0,0,0};
  for(int kb=0; kb<3; ++kb){
    int ta = tloc + r0 + kb - 1;
    int tb = tloc + r1 + kb - 1;
    bool va = (ta>=0) && (ta<1024);
    bool vb = (tb>=0) && (tb<1024);
    const unsigned short* pa = A + ((size_t)bidx*1024 + ta)*384;
    const unsigned short* pb = A + ((size_t)bidx*1024 + tb)*384;
    for(int c0=0; c0<384; c0+=32){
      int k0 = kb*384 + c0;
      short8 a0 = va ? *reinterpret_cast<const short8*>(pa + c0 + kl0*8) : z8;
      short8 a1 = vb ? *reinterpret_cast<const short8*>(pb + c0 + kl1*8) : z8;
      short8 b0 = *reinterpret_cast<const short8*>(W + (size_t)(n0+r0)*1152 + k0 + kl0*8);
      short8 b1 = *reinterpret_cast<const short8*>(W + (size_t)(n0+r1)*1152 + k0 + kl1*8);
      __syncthreads();
      *reinterpret_cast<short8*>(As + u0*8) = a0;
      *reinterpret_cast<short8*>(As + u1*8) = a1;
      *reinterpret_cast<short8*>(Bs + u0*8) = b0;
      *reinterpret_cast<short8*>(Bs + u1*8) = b1;
      __syncthreads();
      short8 af[4], bfr[4];
      #pragma unroll
      for(int f=0;f<4;++f){
        int row = wm*64 + f*16 + ml;
        int un  = row*4 + (kg ^ ((row>>1)&3));
        af[f] = *reinterpret_cast<const short8*>(As + un*8);
        int rowb = wn*64 + f*16 + ml;
        int ub   = rowb*4 + (kg ^ ((rowb>>1)&3));
        bfr[f] = *reinterpret_cast<const short8*>(Bs + ub*8);
      }
      #pragma unroll
      for(int i=0;i<4;++i)
        #pragma unroll
        for(int j=0;j<4;++j)
          acc[i][j] = __builtin_amdgcn_mfma_f32_16x16x32_bf16(af[i], bfr[j], acc[i][j], 0, 0, 0);
    }
  }
  #pragma unroll
  for(int i=0;i<4;++i){
    int rb = m0 + wm*64 + i*16 + kg*4;
    #pragma unroll
    for(int j=0;j<4;++j){
      int col = n0 + wn*64 + j*16 + ml;
      float sc = g[col]*rsqrtf(bv[col]+1e-5f);
      float mm = bm[col], bbv = bb[col], bi = bias[col];
      #pragma unroll
      for(int r=0;r<4;++r){
        float yv = geluf(acc[i][j][r] + bi);
        yv = (yv - mm)*sc + bbv;
        outb[(size_t)(rb+r)*768 + col] = f2bf(yv);
        outf[(size_t)(rb+r)*768 + col] = yv;
      }
    }
  }
}

// ---------------- in_proj MFMA (reg-staged, r5-proven): M=8192 N=3328 K=768 ----------------
// Output split: cols 0..1535 -> Z [8192][1536], cols 1536..3327 -> XB [8192][1792].
__global__ __launch_bounds__(256) void inproj_mfma(const unsigned short* __restrict__ A,
                                                   const unsigned short* __restrict__ B,
                                                   float* __restrict__ Z, float* __restrict__ XB){
  __shared__ unsigned short As[4096], Bs[4096];
  const int tid = threadIdx.x;
  const int lane = tid & 63, wave = tid >> 6;
  const int wm = wave & 1, wn = wave >> 1;
  const int m0 = blockIdx.y*128, n0 = blockIdx.x*128;
  f32x4 acc[4][4];
  #pragma unroll
  for(int i=0;i<4;++i)
    #pragma unroll
    for(int j=0;j<4;++j) acc[i][j] = (f32x4){0.f,0.f,0.f,0.f};
  const int u0 = tid, u1 = tid + 256;
  const int r0 = u0>>2, kl0 = (u0&3) ^ ((r0>>1)&3);
  const int r1 = u1>>2, kl1 = (u1&3) ^ ((r1>>1)&3);
  const int kg = lane>>4, ml = lane&15;
  for(int k0=0;k0<768;k0+=32){
    short8 a0 = *reinterpret_cast<const short8*>(A + (size_t)(m0+r0)*768 + k0 + kl0*8);
    short8 a1 = *reinterpret_cast<const short8*>(A + (size_t)(m0+r1)*768 + k0 + kl1*8);
    short8 b0 = *reinterpret_cast<const short8*>(B + (size_t)(n0+r0)*768 + k0 + kl0*8);
    short8 b1 = *reinterpret_cast<const short8*>(B + (size_t)(n0+r1)*768 + k0 + kl1*8);
    __syncthreads();
    *reinterpret_cast<short8*>(As + u0*8) = a0;
    *reinterpret_cast<short8*>(As + u1*8) = a1;
    *reinterpret_cast<short8*>(Bs + u0*8) = b0;
    *reinterpret_cast<short8*>(Bs + u1*8) = b1;
    __syncthreads();
    short8 af[4], bfr[4];
    #pragma unroll
    for(int f=0;f<4;++f){
      int row = wm*64 + f*16 + ml;
      int un  = row*4 + (kg ^ ((row>>1)&3));
      af[f] = *reinterpret_cast<const short8*>(As + un*8);
      int rowb = wn*64 + f*16 + ml;
      int ub   = rowb*4 + (kg ^ ((rowb>>1)&3));
      bfr[f] = *reinterpret_cast<const short8*>(Bs + ub*8);
    }
    #pragma unroll
    for(int i=0;i<4;++i)
      #pragma unroll
      for(int j=0;j<4;++j)
        acc[i][j] = __builtin_amdgcn_mfma_f32_16x16x32_bf16(af[i], bfr[j], acc[i][j], 0, 0, 0);
  }
  float* op; int cb; int stride;
  if(n0 < 1536){ op = Z;  cb = n0;        stride = 1536; }
  else         { op = XB; cb = n0 - 1536; stride = 1792; }
  #pragma unroll
  for(int i=0;i<4;++i){
    int rb = m0 + wm*64 + i*16 + kg*4;
    #pragma unroll
    for(int j=0;j<4;++j){
      int col = cb + wn*64 + j*16 + ml;
      #pragma unroll
      for(int r=0;r<4;++r)
        op[(size_t)(rb+r)*stride + col] = acc[i][j][r];
    }
  }
}

// ---------------- dt GEMM (fp32, row-major h3) + softplus + dA, fused ----------------
__global__ __launch_bounds__(256) void dtgemm2_k(const float* __restrict__ h3f, const float* __restrict__ W,
                                                 const float* __restrict__ dt_bias, const float* __restrict__ A_log,
                                                 float* __restrict__ dt, float* __restrict__ dA){
  __shared__ float Ws[12][768];
  __shared__ float Ah[12], Bh[12];
  int tid = threadIdx.x;
  for(int idx=tid; idx<9216; idx+=256){
    int hh = idx/768, k = idx - hh*768;
    Ws[hh][k] = W[(size_t)(3328+hh)*768 + k];
  }
  if(tid<12){ Ah[tid] = -expf(A_log[tid]); Bh[tid] = dt_bias[tid]; }
  __syncthreads();
  int wave = tid>>6, lane = tid&63;
  int m = blockIdx.x*4 + wave;
  const float* xr = h3f + (size_t)m*768;
  float xv[12];
  #pragma unroll
  for(int q=0;q<12;++q) xv[q] = xr[q*64+lane];
  float res[12];
  #pragma unroll
  for(int h=0;h<12;++h){
    float acc = 0.f;
    #pragma unroll
    for(int q=0;q<12;++q) acc = fmaf(xv[q], Ws[h][q*64+lane], acc);
    #pragma unroll
    for(int off=32;off;off>>=1) acc += __shfl_xor(acc, off);
    res[h] = acc;
  }
  if(lane==0){
    #pragma unroll
    for(int h=0;h<12;++h){
      float sp = softplusf(res[h] + Bh[h]);
      dt[(size_t)m*12+h] = sp;
      dA[(size_t)m*12+h] = expf(sp*Ah[h]);
    }
  }
}

// ---------------- depthwise causal conv k=4 + silu + split (float4, compact XB) ----------------
__global__ void dwconv_k(const float* __restrict__ XB, const float* __restrict__ cw,
                         const float* __restrict__ cb, float* __restrict__ xs,
                         float* __restrict__ Bo, float* __restrict__ Co){
  int gid = blockIdx.x*256 + threadIdx.x;   // 8192*448
  int c4 = gid % 448;
  int m = gid / 448;
  int t = m & 1023;
  int c = c4*4;
  float wA[4][4];
  #pragma unroll
  for(int i=0;i<4;++i)
    *reinterpret_cast<float4*>(wA[i]) = *reinterpret_cast<const float4*>(&cw[(c+i)*4]);
  float4 bi = *reinterpret_cast<const float4*>(&cb[c]);
  float av[4] = {bi.x, bi.y, bi.z, bi.w};
  #pragma unroll
  for(int j=0;j<4;++j){
    int tt = t - 3 + j;
    if(tt >= 0){
      float4 xv = *reinterpret_cast<const float4*>(&XB[(size_t)(m-3+j)*1792 + c]);
      av[0] = fmaf(wA[0][j], xv.x, av[0]);
      av[1] = fmaf(wA[1][j], xv.y, av[1]);
      av[2] = fmaf(wA[2][j], xv.z, av[2]);
      av[3] = fmaf(wA[3][j], xv.w, av[3]);
    }
  }
  float4 res = make_float4(siluf(av[0]), siluf(av[1]), siluf(av[2]), siluf(av[3]));
  if(c4 < 384)      *reinterpret_cast<float4*>(&xs[(size_t)m*1536 + c])        = res;
  else if(c4 < 416) *reinterpret_cast<float4*>(&Bo[(size_t)m*128 + (c-1536)])  = res;
  else              *reinterpret_cast<float4*>(&Co[(size_t)m*128 + (c-1664)])  = res;
}

// ---------------- per-chunk inclusive cumprod of dA ----------------
__global__ void cumda_k(const float* __restrict__ dA, float* __restrict__ cda){
  __shared__ float ld[1024];
  int bh = blockIdx.x; int b = bh/12, hh = bh - b*12;
  int tid = threadIdx.x;
  for(int i=tid;i<1024;i+=128) ld[i] = dA[((size_t)b*1024 + i)*12 + hh];
  __syncthreads();
  for(int c=0;c<8;++c){
    int base = c*128;
    for(int off=1;off<128;off<<=1){
      float v = ld[base+tid];
      if(tid>=off) v *= ld[base+tid-off];
      __syncthreads();
      ld[base+tid] = v;
      __syncthreads();
    }
  }
  for(int i=tid;i<1024;i+=128) cda[(size_t)bh*1024 + i] = ld[i];
}

// ---------------- SSM scan pass 1: per-chunk local scan (EXACT r5-proven version) ----------------
#define SSTEP(E, BQE, CQE) \
  s[0][jj*4+E] = fmaf(s[0][jj*4+E], dav, c0*BQE); y0 = fmaf(s[0][jj*4+E], CQE, y0); \
  s[1][jj*4+E] = fmaf(s[1][jj*4+E], dav, c1*BQE); y1 = fmaf(s[1][jj*4+E], CQE, y1); \
  s[2][jj*4+E] = fmaf(s[2][jj*4+E], dav, c2*BQE); y2 = fmaf(s[2][jj*4+E], CQE, y2); \
  s[3][jj*4+E] = fmaf(s[3][jj*4+E], dav, c3*BQE); y3 = fmaf(s[3][jj*4+E], CQE, y3);

__global__ __launch_bounds__(128) void scan_chunk_k(float* __restrict__ xs,
    const float* __restrict__ Bm, const float* __restrict__ Cm,
    const float* __restrict__ dtb, const float* __restrict__ dAb,
    const float* __restrict__ Dv, float* __restrict__ sfin){
  const int c = blockIdx.x, h = blockIdx.y, b = blockIdx.z;
  const int tid = threadIdx.x;
  const int ng = tid & 3, pg = tid >> 2;   // p = pg*4+i, n = ng*32+...
  __shared__ float lx[16][128], lB[16][144], lC[16][144], ly[16][128];
  __shared__ float ldt[16], lda_[16];
  float s[4][32];
  #pragma unroll
  for(int i=0;i<4;++i)
    #pragma unroll
    for(int j=0;j<32;++j) s[i][j]=0.f;
  const float Dh = Dv[h];
  const size_t mb = (size_t)b*1024 + (size_t)c*128;
  for(int t0=0;t0<128;t0+=16){
    for(int idx=tid; idx<2048; idx+=128){
      int tl = idx>>7, cc = idx&127;
      lx[tl][cc] = xs[(mb+t0+tl)*1536 + h*128 + cc];
      int slot = (cc>>5)*36 + (cc&31);
      lB[tl][slot] = Bm[(mb+t0+tl)*128 + cc];
      lC[tl][slot] = Cm[(mb+t0+tl)*128 + cc];
    }
    if(tid<16){
      ldt[tid]  = dtb[(mb+t0+tid)*12 + h];
      lda_[tid] = dAb[(mb+t0+tid)*12 + h];
    }
    __syncthreads();
    for(int tl=0; tl<16; ++tl){
      float dtv = ldt[tl], dav = lda_[tl];
      float4 xq = *reinterpret_cast<const float4*>(&lx[tl][pg*4]);
      float c0 = dtv*xq.x, c1 = dtv*xq.y, c2 = dtv*xq.z, c3 = dtv*xq.w;
      float y0=0.f,y1=0.f,y2=0.f,y3=0.f;
      #pragma unroll
      for(int jj=0;jj<8;++jj){
        float4 bq = *reinterpret_cast<const float4*>(&lB[tl][ng*36+jj*4]);
        float4 cq = *reinterpret_cast<const float4*>(&lC[tl][ng*36+jj*4]);
        SSTEP(0, bq.x, cq.x)
        SSTEP(1, bq.y, cq.y)
        SSTEP(2, bq.z, cq.z)
        SSTEP(3, bq.w, cq.w)
      }
      y0 += __shfl_xor(y0,1); y0 += __shfl_xor(y0,2);
      y1 += __shfl_xor(y1,1); y1 += __shfl_xor(y1,2);
      y2 += __shfl_xor(y2,1); y2 += __shfl_xor(y2,2);
      y3 += __shfl_xor(y3,1); y3 += __shfl_xor(y3,2);
      if(ng==0) *reinterpret_cast<float4*>(&ly[tl][pg*4]) = make_float4(y0,y1,y2,y3);
    }
    __syncthreads();
    for(int idx=tid; idx<2048; idx+=128){
      int tl = idx>>7, cc = idx&127;
      xs[(mb+t0+tl)*1536 + h*128 + cc] = ly[tl][cc] + Dh*lx[tl][cc];
    }
    __syncthreads();
  }
  // store local final state, [n][p] layout
  float* dst = sfin + ((size_t)(b*12+h)*8 + c)*16384;
  #pragma unroll
  for(int jj=0;jj<8;++jj)
    #pragma unroll
    for(int e=0;e<4;++e){
      int n = ng*32 + jj*4 + e;
      *reinterpret_cast<float4*>(&dst[(size_t)n*128 + pg*4]) =
        make_float4(s[0][jj*4+e], s[1][jj*4+e], s[2][jj*4+e], s[3][jj*4+e]);
    }
}

// ---------------- SSM scan pass 2: inter-chunk correction y += cumP * (C . S_init) ----------------
__global__ __launch_bounds__(256) void correct_k(const float* __restrict__ Cm,
    const float* __restrict__ cumdA, const float* __restrict__ sfin,
    float* __restrict__ ys){
  const int c = blockIdx.x + 1, h = blockIdx.y, b = blockIdx.z;
  const int tid = threadIdx.x;
  const size_t bh = (size_t)b*12 + h;
  __shared__ float Sl[16][128];
  __shared__ float Cl[16][132];
  __shared__ float cumP[128];
  __shared__ float coefs[8];
  if(tid==0){
    float cf = 1.f;
    for(int cp=c-1; cp>=0; --cp){
      coefs[cp] = cf;
      cf *= cumdA[bh*1024 + (size_t)cp*128 + 127];
    }
  }
  if(tid<128) cumP[tid] = cumdA[bh*1024 + (size_t)c*128 + tid];
  __syncthreads();
  const int tp = tid>>4, tt = tid&15;
  float acc[8][8];
  #pragma unroll
  for(int i=0;i<8;++i)
    #pragma unroll
    for(int j=0;j<8;++j) acc[i][j]=0.f;
  const size_t mb = (size_t)b*1024 + (size_t)c*128;
  for(int n0=0;n0<128;n0+=16){
    {
      int kk = tid>>4, po = tid&15;
      float4 v0 = {0,0,0,0}, v1 = {0,0,0,0};
      for(int cp=0; cp<c; ++cp){
        const float* sp = sfin + ((bh*8 + cp)*16384) + (size_t)(n0+kk)*128 + po*8;
        float4 a0 = *reinterpret_cast<const float4*>(sp);
        float4 a1 = *reinterpret_cast<const float4*>(sp+4);
        float cf = coefs[cp];
        v0.x = fmaf(cf,a0.x,v0.x); v0.y = fmaf(cf,a0.y,v0.y);
        v0.z = fmaf(cf,a0.z,v0.z); v0.w = fmaf(cf,a0.w,v0.w);
        v1.x = fmaf(cf,a1.x,v1.x); v1.y = fmaf(cf,a1.y,v1.y);
        v1.z = fmaf(cf,a1.z,v1.z); v1.w = fmaf(cf,a1.w,v1.w);
      }
      *reinterpret_cast<float4*>(&Sl[kk][po*8])   = v0;
      *reinterpret_cast<float4*>(&Sl[kk][po*8+4]) = v1;
    }
    #pragma unroll
    for(int e=0;e<8;++e){
      int idx = tid*8 + e; int tl = idx>>4, kk = idx&15;
      Cl[kk][tl] = Cm[(mb + tl)*128 + n0 + kk];
    }
    __syncthreads();
    #pragma unroll
    for(int kk=0;kk<16;++kk){
      float4 sa = *reinterpret_cast<const float4*>(&Sl[kk][tp*8]);
      float4 sb = *reinterpret_cast<const float4*>(&Sl[kk][tp*8+4]);
      float4 ca = *reinterpret_cast<const float4*>(&Cl[kk][tt*8]);
      float4 cb = *reinterpret_cast<const float4*>(&Cl[kk][tt*8+4]);
      float sv[8] = {sa.x,sa.y,sa.z,sa.w,sb.x,sb.y,sb.z,sb.w};
      float cv[8] = {ca.x,ca.y,ca.z,ca.w,cb.x,cb.y,cb.z,cb.w};
      #pragma unroll
      for(int i=0;i<8;++i)
        #pragma unroll
        for(int j=0;j<8;++j) acc[i][j] = fmaf(sv[i], cv[j], acc[i][j]);
    }
    __syncthreads();
  }
  #pragma unroll
  for(int j=0;j<8;++j){
    int tl = tt*8 + j;
    float cp = cumP[tl];
    float* yp = ys + (mb + tl)*1536 + h*128 + tp*8;
    float4 y0 = *reinterpret_cast<float4*>(yp);
    float4 y1 = *reinterpret_cast<float4*>(yp+4);
    y0.x += cp*acc[0][j]; y0.y += cp*acc[1][j]; y0.z += cp*acc[2][j]; y0.w += cp*acc[3][j];
    y1.x += cp*acc[4][j]; y1.y += cp*acc[5][j]; y1.z += cp*acc[6][j]; y1.w += cp*acc[7][j];
    *reinterpret_cast<float4*>(yp)   = y0;
    *reinterpret_cast<float4*>(yp+4) = y1;
  }
}

// ---------------- gating: y*silu(z), RMSNorm, partitioned mean-accumulate (r5-proven) ----------------
__global__ void gate_k(const float* __restrict__ ys, const float* __restrict__ Z,
                       const float* __restrict__ nw, float* __restrict__ ybp){
  int m = blockIdx.x;
  int b = m >> 10, t = m & 1023;
  int tid = threadIdx.x;
  float gvals[6];
  float ss = 0.0f;
  #pragma unroll
  for(int r=0;r<6;++r){
    int c = r*256 + tid;
    float yv = ys[(size_t)m*1536 + c];
    float zv = Z[(size_t)m*1536 + c];
    float gv = yv * siluf(zv);
    gvals[r] = gv;
    ss = fmaf(gv, gv, ss);
  }
  #pragma unroll
  for(int off=32;off;off>>=1) ss += __shfl_xor(ss, off);
  __shared__ float red[4];
  if((tid&63)==0) red[tid>>6] = ss;
  __syncthreads();
  float tot = red[0]+red[1]+red[2]+red[3];
  float scale = rsqrtf(tot*(1.0f/1536.0f) + 1e-5f);
  float* dst = ybp + ((size_t)(t&7)*8 + b)*1536;
  #pragma unroll
  for(int r=0;r<6;++r){
    int c = r*256 + tid;
    atomicAdd(&dst[c], gvals[r]*scale*nw[c]);
  }
}

// ---------------- ybar mean: sum 8 partitions, /1024 ----------------
__global__ void ybm_k(const float* __restrict__ ybp, float* __restrict__ ybm){
  int idx = blockIdx.x*256 + threadIdx.x;   // 12288
  float s = 0.0f;
  #pragma unroll
  for(int p=0;p<8;++p) s += ybp[(size_t)p*12288 + idx];
  ybm[idx] = s * (1.0f/1024.0f);
}

__global__ void rep_k(const float* __restrict__ ybm, const float* __restrict__ W,
                      float* __restrict__ rep){
  int wid  = (blockIdx.x<<2) + (threadIdx.x>>6);
  int lane = threadIdx.x & 63;
  int b = wid / 768, o = wid % 768;
  const float* xr = ybm + (size_t)b*1536;
  const float* wr = W + (size_t)o*1536;
  float acc = 0.0f;
  for(int c=lane;c<1536;c+=64) acc = fmaf(xr[c], wr[c], acc);
  #pragma unroll
  for(int off=32;off;off>>=1) acc += __shfl_xor(acc, off);
  if(lane==0) rep[wid] = acc;
}

__global__ void fc1_k(const float* __restrict__ rep, const float* __restrict__ W,
                      const float* __restrict__ bias, const float* __restrict__ g,
                      const float* __restrict__ bb, const float* __restrict__ m,
                      const float* __restrict__ v, float* __restrict__ out){
  int wid  = (blockIdx.x<<2) + (threadIdx.x>>6);
  int lane = threadIdx.x & 63;
  int b = wid >> 10, o = wid & 1023;
  const float* xr = rep + (size_t)b*768;
  const float* wr = W + (size_t)o*768;
  float acc = 0.0f;
  for(int c=lane;c<768;c+=64) acc = fmaf(xr[c], wr[c], acc);
  #pragma unroll
  for(int off=32;off;off>>=1) acc += __shfl_xor(acc, off);
  if(lane==0){
    float val = acc + bias[o];
    float sc = g[o]*rsqrtf(v[o]+1e-5f);
    val = (val - m[o])*sc + bb[o];
    out[wid] = fmaxf(val, 0.0f);
  }
}

__global__ void fc2_k(const float* __restrict__ h1, const float* __restrict__ W,
                      const float* __restrict__ bias, float* __restrict__ out){
  int wid  = (blockIdx.x<<2) + (threadIdx.x>>6);
  int lane = threadIdx.x & 63;
  int b = wid / 27, o = wid % 27;
  const float* xr = h1 + (size_t)b*1024;
  const float* wr = W + (size_t)o*1024;
  float acc = 0.0f;
  for(int c=lane;c<1024;c+=64) acc = fmaf(xr[c], wr[c], acc);
  #pragma unroll
  for(int off=32;off;off>>=1) acc += __shfl_xor(acc, off);
  if(lane==0) out[wid] = acc + bias[o];
}

// ---------------- workspace layout (float offsets) ----------------
// Footprint: 54,945,792 floats (proven cap).
#define OFF_H1     0u           // 3,145,728 fp32 [conv1 -> xpose1]
#define OFF_T1     3145728u     // ushort x 3,145,728 [xpose1 -> conv2]
#define OFF_T2     4718592u     // ushort x 3,145,728 [conv2 -> conv3]
#define OFF_H3T    6291456u     // ushort x 6,291,456 [conv3 -> inproj]
#define OFF_WB     9437184u     // ushort x 2,555,904 [wprep -> inproj]
#define OFF_W2R    10715136u    // ushort x 221,184
#define OFF_W3R    10825728u    // ushort x 884,736 ; early region ends 11,268,096
#define OFF_Z      12582912u    // 12,582,912 fp32 [inproj -> gate]
#define OFF_XB     25165824u    // 14,680,064 fp32 [inproj -> dwconv] ends 39,845,888
#define OFF_XS     39944192u    // 12,582,912 (h3f first, then xs/ys)
#define OFF_H3F    39944192u    // 6,291,456 fp32 [conv3 -> dtgemm2, before dwconv]
#define OFF_B      52527104u    // 1,048,576
#define OFF_C      53575680u    // 1,048,576
#define OFF_DT     54624256u    // 98,304
#define OFF_DA     54722560u    // 98,304
#define OFF_SLOT98K 54820864u   // 98,304: cda (cumda->correct) then ybp (gate->ybm)
#define OFF_YBM    54919168u    // 12,288
#define OFF_REP    54931456u    // 6,144
#define OFF_FC1    54937600u    // 8,192 ; end = 54,945,792
#define OFF_SFIN   0u           // 12,582,912 [scan -> correct], early region dead

extern "C" void kernel_launch(void* const* d_in, const int* in_sizes, int n_in,
                              void* d_out, int out_size, void* d_ws, size_t ws_size,
                              hipStream_t stream){
  const float* x       = (const float*)d_in[0];
  const float* w1      = (const float*)d_in[1];
  const float* b1      = (const float*)d_in[2];
  const float* bn1g    = (const float*)d_in[3];
  const float* bn1b    = (const float*)d_in[4];
  const float* bn1m    = (const float*)d_in[5];
  const float* bn1v    = (const float*)d_in[6];
  const float* w2      = (const float*)d_in[7];
  const float* b2      = (const float*)d_in[8];
  const float* bn2g    = (const float*)d_in[9];
  const float* bn2b    = (const float*)d_in[10];
  const float* bn2m    = (const float*)d_in[11];
  const float* bn2v    = (const float*)d_in[12];
  const float* w3      = (const float*)d_in[13];
  const float* b3      = (const float*)d_in[14];
  const float* bn3g    = (const float*)d_in[15];
  const float* bn3b    = (const float*)d_in[16];
  const float* bn3m    = (const float*)d_in[17];
  const float* bn3v    = (const float*)d_in[18];
  const float* ipw     = (const float*)d_in[19];
  const float* convw   = (const float*)d_in[20];
  const float* convb   = (const float*)d_in[21];
  const float* dtbias  = (const float*)d_in[22];
  const float* Alog    = (const float*)d_in[23];
  const float* Dvec    = (const float*)d_in[24];
  const float* normw   = (const float*)d_in[25];
  const float* opw     = (const float*)d_in[26];
  const float* fc1w    = (const float*)d_in[27];
  const float* fc1b    = (const float*)d_in[28];
  const float* bncg    = (const float*)d_in[29];
  const float* bncb    = (const float*)d_in[30];
  const float* bncm    = (const float*)d_in[31];
  const float* bncv    = (const float*)d_in[32];
  const float* fc2w    = (const float*)d_in[33];
  const float* fc2b    = (const float*)d_in[34];

  float* ws   = (float*)d_ws;
  float* h1   = ws + OFF_H1;
  unsigned short* T1  = (unsigned short*)(ws + OFF_T1);
  unsigned short* T2  = (unsigned short*)(ws + OFF_T2);
  unsigned short* h3t = (unsigned short*)(ws + OFF_H3T);
  unsigned short* Wb  = (unsigned short*)(ws + OFF_WB);
  unsigned short* w2r = (unsigned short*)(ws + OFF_W2R);
  unsigned short* w3r = (unsigned short*)(ws + OFF_W3R);
  float* Zb   = ws + OFF_Z;
  float* XBb  = ws + OFF_XB;
  float* xsb  = ws + OFF_XS;
  float* h3f  = ws + OFF_H3F;
  float* Bb   = ws + OFF_B;
  float* Cb   = ws + OFF_C;
  float* dtb  = ws + OFF_DT;
  float* dAb  = ws + OFF_DA;
  float* slot = ws + OFF_SLOT98K;
  float* ybm  = ws + OFF_YBM;
  float* rep  = ws + OFF_REP;
  float* f1b  = ws + OFF_FC1;
  float* sfin = ws + OFF_SFIN;
  float* outp = (float*)d_out;

  conv1_k<<<dim3(8,24,8),  256, 0, stream>>>(x, w1, b1, bn1g, bn1b, bn1m, bn1v, h1);
  xpose1_k<<<dim3(64,6,8), 256, 0, stream>>>(h1, T1);
  wprep_k<<<14304, 256, 0, stream>>>(ipw, w2, w3, Wb, w2r, w3r);
  conv2_mfma<<<dim3(3,64), 256, 0, stream>>>(T1, w2r, b2, bn2g, bn2b, bn2m, bn2v, T2);
  conv3_mfma<<<dim3(6,64), 256, 0, stream>>>(T2, w3r, b3, bn3g, bn3b, bn3m, bn3v, h3t, h3f);
  dtgemm2_k<<<2048, 256, 0, stream>>>(h3f, ipw, dtbias, Alog, dtb, dAb);
  inproj_mfma<<<dim3(26,64), 256, 0, stream>>>(h3t, Wb, Zb, XBb);
  dwconv_k<<<14336, 256, 0, stream>>>(XBb, convw, convb, xsb, Bb, Cb);
  cumda_k<<<96, 128, 0, stream>>>(dAb, slot);                        // cda = slot
  scan_chunk_k<<<dim3(8,12,8), 128, 0, stream>>>(xsb, Bb, Cb, dtb, dAb, Dvec, sfin);
  correct_k<<<dim3(7,12,8), 256, 0, stream>>>(Cb, slot, sfin, xsb);  // reads cda
  hipMemsetAsync(slot, 0, 98304*sizeof(float), stream);              // zero ybp
  gate_k<<<8192, 256, 0, stream>>>(xsb, Zb, normw, slot);            // ybp = slot (atomics)
  ybm_k<<<48, 256, 0, stream>>>(slot, ybm);
  rep_k<<<1536, 256, 0, stream>>>(ybm, opw, rep);
  fc1_k<<<2048, 256, 0, stream>>>(rep, fc1w, fc1b, bncg, bncb, bncm, bncv, f1b);
  fc2_k<<<54, 256, 0, stream>>>(f1b, fc2w, fc2b, outp);
}

// Round 11
// 649.233 us; speedup vs baseline: 1.3226x; 1.1568x over previous
//
#include <hip/hip_runtime.h>
#include <math.h>

#define DEV __device__ __forceinline__

DEV float geluf(float x){ return 0.5f*x*(1.0f+erff(x*0.7071067811865476f)); }
DEV float siluf(float x){ return x/(1.0f+expf(-x)); }
DEV float softplusf(float x){ return fmaxf(x,0.0f)+log1pf(expf(-fabsf(x))); }
DEV unsigned short f2bf(float f){
  unsigned int u = __float_as_uint(f);
  unsigned int r = (u + 0x7fffu + ((u>>16)&1u)) >> 16;
  return (unsigned short)r;
}
DEV float bf2f(unsigned short u){ return __uint_as_float(((unsigned int)u)<<16); }

typedef __attribute__((ext_vector_type(8))) short short8;
typedef __attribute__((ext_vector_type(4))) float f32x4;

// ---------------- conv1: (8,12,4096) -> (8,192,2048), k=5 s=2 p=2, gelu+bn ----------------
__global__ void conv1_k(const float* __restrict__ x, const float* __restrict__ w,
                        const float* __restrict__ bias,
                        const float* __restrict__ g, const float* __restrict__ bb,
                        const float* __restrict__ m, const float* __restrict__ v,
                        float* __restrict__ out){
  int t  = blockIdx.x*256 + threadIdx.x;
  int og = blockIdx.y;
  int b  = blockIdx.z;
  const float* xb = x + (size_t)b*12*4096;
  float acc[8];
  #pragma unroll
  for(int oo=0;oo<8;++oo) acc[oo] = bias[og*8+oo];
  for(int i=0;i<12;++i){
    float xv[5];
    #pragma unroll
    for(int k=0;k<5;++k){
      int src = 2*t + k - 2;
      xv[k] = (src>=0 && src<4096) ? xb[i*4096+src] : 0.0f;
    }
    #pragma unroll
    for(int oo=0;oo<8;++oo){
      const float* wr = w + (size_t)(og*8+oo)*60 + i*5;
      #pragma unroll
      for(int k=0;k<5;++k) acc[oo] = fmaf(wr[k], xv[k], acc[oo]);
    }
  }
  #pragma unroll
  for(int oo=0;oo<8;++oo){
    int o = og*8+oo;
    float y = geluf(acc[oo]);
    float sc = g[o]*rsqrtf(v[o]+1e-5f);
    y = (y-m[o])*sc + bb[o];
    out[(size_t)b*192*2048 + (size_t)o*2048 + t] = y;
  }
}

// ---------------- transpose-cast h1 [b][i][t] fp32 -> T1 [b*2048+t][192] bf16 ----------------
__global__ void xpose1_k(const float* __restrict__ h1, unsigned short* __restrict__ T1){
  __shared__ float tile[32][33];
  int t0 = blockIdx.x*32, i0 = blockIdx.y*32, b = blockIdx.z;
  int c = threadIdx.x & 31, r4 = threadIdx.x >> 5;
  const float* src = h1 + (size_t)b*393216;
  #pragma unroll
  for(int i=0;i<4;++i){ int r = r4 + i*8; tile[r][c] = src[(size_t)(i0+r)*2048 + t0 + c]; }
  __syncthreads();
  unsigned short* dst = T1 + (size_t)b*2048*192;
  #pragma unroll
  for(int i=0;i<4;++i){ int r = r4 + i*8;
    dst[(size_t)(t0+r)*192 + i0 + c] = f2bf(tile[c][r]);
  }
}

// ---------------- fused weight prep: in_proj W bf16 + w2/w3 reorder bf16 ----------------
__global__ void wprep_k(const float* __restrict__ ipw, const float* __restrict__ w2,
                        const float* __restrict__ w3, unsigned short* __restrict__ Wb,
                        unsigned short* __restrict__ w2r, unsigned short* __restrict__ w3r){
  int gid = blockIdx.x*256 + threadIdx.x;
  if(gid < 2555904){
    Wb[gid] = f2bf(ipw[gid]);
  } else if(gid < 2555904+221184){
    int g2 = gid - 2555904;
    int o = g2 / 576, rem = g2 - o*576, k = rem / 192, i = rem - k*192;
    w2r[g2] = f2bf(w2[(size_t)o*576 + i*3 + k]);
  } else if(gid < 2555904+221184+884736){
    int g3 = gid - 2555904 - 221184;
    int o = g3 / 1152, rem = g3 - o*1152, k = rem / 384, i = rem - k*384;
    w3r[g3] = f2bf(w3[(size_t)o*1152 + i*3 + k]);
  }
}

// ---------------- conv2 as MFMA GEMM ----------------
__global__ __launch_bounds__(256) void conv2_mfma(const unsigned short* __restrict__ A,
                                                  const unsigned short* __restrict__ W,
                                                  const float* __restrict__ bias,
                                                  const float* __restrict__ g, const float* __restrict__ bb,
                                                  const float* __restrict__ bm, const float* __restrict__ bv,
                                                  unsigned short* __restrict__ outb){
  __shared__ unsigned short As[4096], Bs[4096];
  const int tid = threadIdx.x;
  const int lane = tid & 63, wave = tid >> 6;
  const int wm = wave & 1, wn = wave >> 1;
  const int m0 = blockIdx.y*128, n0 = blockIdx.x*128;
  const int bidx = m0 >> 10, tloc = m0 & 1023;
  f32x4 acc[4][4];
  #pragma unroll
  for(int i=0;i<4;++i)
    #pragma unroll
    for(int j=0;j<4;++j) acc[i][j] = (f32x4){0.f,0.f,0.f,0.f};
  const int u0 = tid, u1 = tid + 256;
  const int r0 = u0>>2, kl0 = (u0&3) ^ ((r0>>1)&3);
  const int r1 = u1>>2, kl1 = (u1&3) ^ ((r1>>1)&3);
  const int kg = lane>>4, ml = lane&15;
  const short8 z8 = {0,0,0,0,0,0,0,0};
  for(int kb=0; kb<3; ++kb){
    int ta = 2*(tloc + r0) + kb - 1;
    int tb = 2*(tloc + r1) + kb - 1;
    bool va = (ta>=0) && (ta<2048);
    bool vb = (tb>=0) && (tb<2048);
    const unsigned short* pa = A + ((size_t)bidx*2048 + ta)*192;
    const unsigned short* pb = A + ((size_t)bidx*2048 + tb)*192;
    for(int c0=0; c0<192; c0+=32){
      int k0 = kb*192 + c0;
      short8 a0 = va ? *reinterpret_cast<const short8*>(pa + c0 + kl0*8) : z8;
      short8 a1 = vb ? *reinterpret_cast<const short8*>(pb + c0 + kl1*8) : z8;
      short8 b0 = *reinterpret_cast<const short8*>(W + (size_t)(n0+r0)*576 + k0 + kl0*8);
      short8 b1 = *reinterpret_cast<const short8*>(W + (size_t)(n0+r1)*576 + k0 + kl1*8);
      __syncthreads();
      *reinterpret_cast<short8*>(As + u0*8) = a0;
      *reinterpret_cast<short8*>(As + u1*8) = a1;
      *reinterpret_cast<short8*>(Bs + u0*8) = b0;
      *reinterpret_cast<short8*>(Bs + u1*8) = b1;
      __syncthreads();
      short8 af[4], bfr[4];
      #pragma unroll
      for(int f=0;f<4;++f){
        int row = wm*64 + f*16 + ml;
        int un  = row*4 + (kg ^ ((row>>1)&3));
        af[f] = *reinterpret_cast<const short8*>(As + un*8);
        int rowb = wn*64 + f*16 + ml;
        int ub   = rowb*4 + (kg ^ ((rowb>>1)&3));
        bfr[f] = *reinterpret_cast<const short8*>(Bs + ub*8);
      }
      #pragma unroll
      for(int i=0;i<4;++i)
        #pragma unroll
        for(int j=0;j<4;++j)
          acc[i][j] = __builtin_amdgcn_mfma_f32_16x16x32_bf16(af[i], bfr[j], acc[i][j], 0, 0, 0);
    }
  }
  #pragma unroll
  for(int i=0;i<4;++i){
    int rb = m0 + wm*64 + i*16 + kg*4;
    #pragma unroll
    for(int j=0;j<4;++j){
      int col = n0 + wn*64 + j*16 + ml;
      float sc = g[col]*rsqrtf(bv[col]+1e-5f);
      float mm = bm[col], bbv = bb[col], bi = bias[col];
      #pragma unroll
      for(int r=0;r<4;++r){
        float yv = geluf(acc[i][j][r] + bi);
        yv = (yv - mm)*sc + bbv;
        outb[(size_t)(rb+r)*384 + col] = f2bf(yv);
      }
    }
  }
}

// ---------------- conv3 as MFMA GEMM ----------------
__global__ __launch_bounds__(256) void conv3_mfma(const unsigned short* __restrict__ A,
                                                  const unsigned short* __restrict__ W,
                                                  const float* __restrict__ bias,
                                                  const float* __restrict__ g, const float* __restrict__ bb,
                                                  const float* __restrict__ bm, const float* __restrict__ bv,
                                                  unsigned short* __restrict__ outb,
                                                  float* __restrict__ outf){
  __shared__ unsigned short As[4096], Bs[4096];
  const int tid = threadIdx.x;
  const int lane = tid & 63, wave = tid >> 6;
  const int wm = wave & 1, wn = wave >> 1;
  const int m0 = blockIdx.y*128, n0 = blockIdx.x*128;
  const int bidx = m0 >> 10, tloc = m0 & 1023;
  f32x4 acc[4][4];
  #pragma unroll
  for(int i=0;i<4;++i)
    #pragma unroll
    for(int j=0;j<4;++j) acc[i][j] = (f32x4){0.f,0.f,0.f,0.f};
  const int u0 = tid, u1 = tid + 256;
  const int r0 = u0>>2, kl0 = (u0&3) ^ ((r0>>1)&3);
  const int r1 = u1>>2, kl1 = (u1&3) ^ ((r1>>1)&3);
  const int kg = lane>>4, ml = lane&15;
  const short8 z8 = {0,0,0,0,0,0,0,0};
  for(int kb=0; kb<3; ++kb){
    int ta = tloc + r0 + kb - 1;
    int tb = tloc + r1 + kb - 1;
    bool va = (ta>=0) && (ta<1024);
    bool vb = (tb>=0) && (tb<1024);
    const unsigned short* pa = A + ((size_t)bidx*1024 + ta)*384;
    const unsigned short* pb = A + ((size_t)bidx*1024 + tb)*384;
    for(int c0=0; c0<384; c0+=32){
      int k0 = kb*384 + c0;
      short8 a0 = va ? *reinterpret_cast<const short8*>(pa + c0 + kl0*8) : z8;
      short8 a1 = vb ? *reinterpret_cast<const short8*>(pb + c0 + kl1*8) : z8;
      short8 b0 = *reinterpret_cast<const short8*>(W + (size_t)(n0+r0)*1152 + k0 + kl0*8);
      short8 b1 = *reinterpret_cast<const short8*>(W + (size_t)(n0+r1)*1152 + k0 + kl1*8);
      __syncthreads();
      *reinterpret_cast<short8*>(As + u0*8) = a0;
      *reinterpret_cast<short8*>(As + u1*8) = a1;
      *reinterpret_cast<short8*>(Bs + u0*8) = b0;
      *reinterpret_cast<short8*>(Bs + u1*8) = b1;
      __syncthreads();
      short8 af[4], bfr[4];
      #pragma unroll
      for(int f=0;f<4;++f){
        int row = wm*64 + f*16 + ml;
        int un  = row*4 + (kg ^ ((row>>1)&3));
        af[f] = *reinterpret_cast<const short8*>(As + un*8);
        int rowb = wn*64 + f*16 + ml;
        int ub   = rowb*4 + (kg ^ ((rowb>>1)&3));
        bfr[f] = *reinterpret_cast<const short8*>(Bs + ub*8);
      }
      #pragma unroll
      for(int i=0;i<4;++i)
        #pragma unroll
        for(int j=0;j<4;++j)
          acc[i][j] = __builtin_amdgcn_mfma_f32_16x16x32_bf16(af[i], bfr[j], acc[i][j], 0, 0, 0);
    }
  }
  #pragma unroll
  for(int i=0;i<4;++i){
    int rb = m0 + wm*64 + i*16 + kg*4;
    #pragma unroll
    for(int j=0;j<4;++j){
      int col = n0 + wn*64 + j*16 + ml;
      float sc = g[col]*rsqrtf(bv[col]+1e-5f);
      float mm = bm[col], bbv = bb[col], bi = bias[col];
      #pragma unroll
      for(int r=0;r<4;++r){
        float yv = geluf(acc[i][j][r] + bi);
        yv = (yv - mm)*sc + bbv;
        outb[(size_t)(rb+r)*768 + col] = f2bf(yv);
        outf[(size_t)(rb+r)*768 + col] = yv;
      }
    }
  }
}

// ---------------- in_proj MFMA (reg-staged, r5-proven): M=8192 N=3328 K=768 ----------------
__global__ __launch_bounds__(256) void inproj_mfma(const unsigned short* __restrict__ A,
                                                   const unsigned short* __restrict__ B,
                                                   float* __restrict__ Z, float* __restrict__ XB){
  __shared__ unsigned short As[4096], Bs[4096];
  const int tid = threadIdx.x;
  const int lane = tid & 63, wave = tid >> 6;
  const int wm = wave & 1, wn = wave >> 1;
  const int m0 = blockIdx.y*128, n0 = blockIdx.x*128;
  f32x4 acc[4][4];
  #pragma unroll
  for(int i=0;i<4;++i)
    #pragma unroll
    for(int j=0;j<4;++j) acc[i][j] = (f32x4){0.f,0.f,0.f,0.f};
  const int u0 = tid, u1 = tid + 256;
  const int r0 = u0>>2, kl0 = (u0&3) ^ ((r0>>1)&3);
  const int r1 = u1>>2, kl1 = (u1&3) ^ ((r1>>1)&3);
  const int kg = lane>>4, ml = lane&15;
  for(int k0=0;k0<768;k0+=32){
    short8 a0 = *reinterpret_cast<const short8*>(A + (size_t)(m0+r0)*768 + k0 + kl0*8);
    short8 a1 = *reinterpret_cast<const short8*>(A + (size_t)(m0+r1)*768 + k0 + kl1*8);
    short8 b0 = *reinterpret_cast<const short8*>(B + (size_t)(n0+r0)*768 + k0 + kl0*8);
    short8 b1 = *reinterpret_cast<const short8*>(B + (size_t)(n0+r1)*768 + k0 + kl1*8);
    __syncthreads();
    *reinterpret_cast<short8*>(As + u0*8) = a0;
    *reinterpret_cast<short8*>(As + u1*8) = a1;
    *reinterpret_cast<short8*>(Bs + u0*8) = b0;
    *reinterpret_cast<short8*>(Bs + u1*8) = b1;
    __syncthreads();
    short8 af[4], bfr[4];
    #pragma unroll
    for(int f=0;f<4;++f){
      int row = wm*64 + f*16 + ml;
      int un  = row*4 + (kg ^ ((row>>1)&3));
      af[f] = *reinterpret_cast<const short8*>(As + un*8);
      int rowb = wn*64 + f*16 + ml;
      int ub   = rowb*4 + (kg ^ ((rowb>>1)&3));
      bfr[f] = *reinterpret_cast<const short8*>(Bs + ub*8);
    }
    #pragma unroll
    for(int i=0;i<4;++i)
      #pragma unroll
      for(int j=0;j<4;++j)
        acc[i][j] = __builtin_amdgcn_mfma_f32_16x16x32_bf16(af[i], bfr[j], acc[i][j], 0, 0, 0);
  }
  float* op; int cb; int stride;
  if(n0 < 1536){ op = Z;  cb = n0;        stride = 1536; }
  else         { op = XB; cb = n0 - 1536; stride = 1792; }
  #pragma unroll
  for(int i=0;i<4;++i){
    int rb = m0 + wm*64 + i*16 + kg*4;
    #pragma unroll
    for(int j=0;j<4;++j){
      int col = cb + wn*64 + j*16 + ml;
      #pragma unroll
      for(int r=0;r<4;++r)
        op[(size_t)(rb+r)*stride + col] = acc[i][j][r];
    }
  }
}

// ---------------- dt GEMM (fp32, row-major h3) + softplus, fused ----------------
__global__ __launch_bounds__(256) void dtgemm2_k(const float* __restrict__ h3f, const float* __restrict__ W,
                                                 const float* __restrict__ dt_bias,
                                                 float* __restrict__ dt){
  __shared__ float Ws[12][768];
  __shared__ float Bh[12];
  int tid = threadIdx.x;
  for(int idx=tid; idx<9216; idx+=256){
    int hh = idx/768, k = idx - hh*768;
    Ws[hh][k] = W[(size_t)(3328+hh)*768 + k];
  }
  if(tid<12){ Bh[tid] = dt_bias[tid]; }
  __syncthreads();
  int wave = tid>>6, lane = tid&63;
  int m = blockIdx.x*4 + wave;
  const float* xr = h3f + (size_t)m*768;
  float xv[12];
  #pragma unroll
  for(int q=0;q<12;++q) xv[q] = xr[q*64+lane];
  float res[12];
  #pragma unroll
  for(int h=0;h<12;++h){
    float acc = 0.f;
    #pragma unroll
    for(int q=0;q<12;++q) acc = fmaf(xv[q], Ws[h][q*64+lane], acc);
    #pragma unroll
    for(int off=32;off;off>>=1) acc += __shfl_xor(acc, off);
    res[h] = acc;
  }
  if(lane==0){
    #pragma unroll
    for(int h=0;h<12;++h){
      dt[(size_t)m*12+h] = softplusf(res[h] + Bh[h]);
    }
  }
}

// ---------------- depthwise causal conv k=4 + silu + split (xs fp32, B/C bf16) ----------------
__global__ void dwconv_k(const float* __restrict__ XB, const float* __restrict__ cw,
                         const float* __restrict__ cb, float* __restrict__ xs,
                         unsigned short* __restrict__ Bo, unsigned short* __restrict__ Co){
  int gid = blockIdx.x*256 + threadIdx.x;   // 8192*448
  int c4 = gid % 448;
  int m = gid / 448;
  int t = m & 1023;
  int c = c4*4;
  float wA[4][4];
  #pragma unroll
  for(int i=0;i<4;++i)
    *reinterpret_cast<float4*>(wA[i]) = *reinterpret_cast<const float4*>(&cw[(c+i)*4]);
  float4 bi = *reinterpret_cast<const float4*>(&cb[c]);
  float av[4] = {bi.x, bi.y, bi.z, bi.w};
  #pragma unroll
  for(int j=0;j<4;++j){
    int tt = t - 3 + j;
    if(tt >= 0){
      float4 xv = *reinterpret_cast<const float4*>(&XB[(size_t)(m-3+j)*1792 + c]);
      av[0] = fmaf(wA[0][j], xv.x, av[0]);
      av[1] = fmaf(wA[1][j], xv.y, av[1]);
      av[2] = fmaf(wA[2][j], xv.z, av[2]);
      av[3] = fmaf(wA[3][j], xv.w, av[3]);
    }
  }
  float r0 = siluf(av[0]), r1 = siluf(av[1]), r2 = siluf(av[2]), r3 = siluf(av[3]);
  if(c4 < 384){
    *reinterpret_cast<float4*>(&xs[(size_t)m*1536 + c]) = make_float4(r0,r1,r2,r3);
  } else {
    unsigned long long pk = (unsigned long long)f2bf(r0)
                          | ((unsigned long long)f2bf(r1) << 16)
                          | ((unsigned long long)f2bf(r2) << 32)
                          | ((unsigned long long)f2bf(r3) << 48);
    if(c4 < 416) *reinterpret_cast<unsigned long long*>(&Bo[(size_t)m*128 + (c-1536)]) = pk;
    else         *reinterpret_cast<unsigned long long*>(&Co[(size_t)m*128 + (c-1664)]) = pk;
  }
}

// ---------------- per-chunk cumsum of log dA; cda = exp(la) ----------------
__global__ void cumda_k(const float* __restrict__ dtb, const float* __restrict__ Alog,
                        float* __restrict__ cda, float* __restrict__ lab){
  __shared__ float ld[1024];
  int bh = blockIdx.x; int b = bh/12, hh = bh - b*12;
  int tid = threadIdx.x;
  float Ah = -expf(Alog[hh]);
  for(int i=tid;i<1024;i+=128) ld[i] = dtb[((size_t)b*1024 + i)*12 + hh] * Ah;
  __syncthreads();
  for(int c=0;c<8;++c){
    int base = c*128;
    for(int off=1;off<128;off<<=1){
      float v = ld[base+tid];
      if(tid>=off) v += ld[base+tid-off];
      __syncthreads();
      ld[base+tid] = v;
      __syncthreads();
    }
  }
  for(int i=tid;i<1024;i+=128){
    lab[(size_t)bh*1024 + i] = ld[i];
    cda[(size_t)bh*1024 + i] = expf(ld[i]);
  }
}

// ---------------- SSD chunk kernel: Y_local + chunk states via 3 MFMA GEMMs ----------------
// Per (c,h,b): CB = C@B^T (K=n); M = causal(CB * exp(la_i-la_j)) (hi/lo bf16);
// Y = M@dtX (K=j) + D*x -> xs in place; S[n][p] = wB^T@dtX -> sfin.
__global__ __launch_bounds__(256) void ssd_k(float* __restrict__ xs,
    const unsigned short* __restrict__ Bm, const unsigned short* __restrict__ Cm,
    const float* __restrict__ dtb, const float* __restrict__ lab,
    const float* __restrict__ Dv, float* __restrict__ sfin){
  const int c = blockIdx.x, h = blockIdx.y, b = blockIdx.z;
  const int tid = threadIdx.x;
  const int lane = tid & 63, wave = tid >> 6;
  const int wm = wave & 1, wn = wave >> 1;
  const int kg = lane>>4, ml = lane&15;
  __shared__ unsigned short Cb[16384], Bb[16384], Xt[16384];  // 96 KB
  __shared__ float la[128], dtc[128];
  const size_t mb = (size_t)b*1024 + (size_t)c*128;
  const size_t bh = (size_t)b*12 + h;
  // ---- P1: stage la, dt, Cb=C[t][n], Bb=B[t][n] (swizzled chunk layout) ----
  if(tid < 128){
    la[tid]  = lab[bh*1024 + (size_t)c*128 + tid];
    dtc[tid] = dtb[(mb+tid)*12 + h];
  }
  for(int g = tid; g < 2048; g += 256){
    int r = g >> 4, oct = g & 15;
    int ck = oct >> 2, o = oct & 3;
    int u = ck*4096 + (r*4 + (o ^ ((r>>1)&3)))*8;
    *reinterpret_cast<short8*>(Cb + u) = *reinterpret_cast<const short8*>(Cm + (mb+r)*128 + ck*32 + o*8);
    *reinterpret_cast<short8*>(Bb + u) = *reinterpret_cast<const short8*>(Bm + (mb+r)*128 + ck*32 + o*8);
  }
  __syncthreads();
  // ---- stage Xt = dtX^T[p][j] (scatter-transpose) ----
  for(int a = tid; a < 4096; a += 256){
    int j = a >> 5, pq = a & 31;
    float4 xv = *reinterpret_cast<const float4*>(&xs[(mb+j)*1536 + h*128 + pq*4]);
    float dj = dtc[j];
    int ck = j>>5, o = (j>>3)&3, e = j&7;
    float vv[4] = {xv.x, xv.y, xv.z, xv.w};
    #pragma unroll
    for(int q=0;q<4;++q){
      int p = pq*4+q;
      Xt[ck*4096 + (p*4 + (o ^ ((p>>1)&3)))*8 + e] = f2bf(vv[q]*dj);
    }
  }
  __syncthreads();
  // ---- GEMM1: CB[i][j] = sum_n C[i][n]*B[j][n] ----
  f32x4 accM[4][4];
  #pragma unroll
  for(int i=0;i<4;++i)
    #pragma unroll
    for(int j=0;j<4;++j) accM[i][j] = (f32x4){0.f,0.f,0.f,0.f};
  for(int ck=0;ck<4;++ck){
    short8 af[4], bfr[4];
    #pragma unroll
    for(int f=0;f<4;++f){
      int row = wm*64 + f*16 + ml;
      af[f] = *reinterpret_cast<const short8*>(Cb + ck*4096 + (row*4 + (kg ^ ((row>>1)&3)))*8);
      int rowb = wn*64 + f*16 + ml;
      bfr[f] = *reinterpret_cast<const short8*>(Bb + ck*4096 + (rowb*4 + (kg ^ ((rowb>>1)&3)))*8);
    }
    #pragma unroll
    for(int i=0;i<4;++i)
      #pragma unroll
      for(int j=0;j<4;++j)
        accM[i][j] = __builtin_amdgcn_mfma_f32_16x16x32_bf16(af[i], bfr[j], accM[i][j], 0, 0, 0);
  }
  __syncthreads();   // GEMM1 reads done; Cb/Bb reusable
  // ---- M = causal(CB * exp(la_i - la_j)); hi->Cb, lo->Bb ----
  #pragma unroll
  for(int fj=0;fj<4;++fj){
    int j = wn*64 + fj*16 + ml;
    float laj = la[j];
    int jck = j>>5, jo = (j>>3)&3, je = j&7;
    #pragma unroll
    for(int fi=0;fi<4;++fi){
      #pragma unroll
      for(int r=0;r<4;++r){
        int i = wm*64 + fi*16 + kg*4 + r;
        float v = (j <= i) ? accM[fi][fj][r] * expf(la[i]-laj) : 0.f;
        unsigned short hi = f2bf(v);
        unsigned short lo = f2bf(v - bf2f(hi));
        int idx = jck*4096 + (i*4 + (jo ^ ((i>>1)&3)))*8 + je;
        Cb[idx] = hi; Bb[idx] = lo;
      }
    }
  }
  __syncthreads();
  // ---- GEMM2: Y[t][p] = sum_j (Mhi+Mlo)[t][j] * dtX[j][p]; epilogue += D*x ----
  f32x4 accY[4][4];
  #pragma unroll
  for(int i=0;i<4;++i)
    #pragma unroll
    for(int j=0;j<4;++j) accY[i][j] = (f32x4){0.f,0.f,0.f,0.f};
  for(int ck=0;ck<4;++ck){
    short8 aH[4], aL[4], bX[4];
    #pragma unroll
    for(int f=0;f<4;++f){
      int row = wm*64 + f*16 + ml;
      int ua = ck*4096 + (row*4 + (kg ^ ((row>>1)&3)))*8;
      aH[f] = *reinterpret_cast<const short8*>(Cb + ua);
      aL[f] = *reinterpret_cast<const short8*>(Bb + ua);
      int rowp = wn*64 + f*16 + ml;
      bX[f] = *reinterpret_cast<const short8*>(Xt + ck*4096 + (rowp*4 + (kg ^ ((rowp>>1)&3)))*8);
    }
    #pragma unroll
    for(int i=0;i<4;++i)
      #pragma unroll
      for(int j=0;j<4;++j){
        accY[i][j] = __builtin_amdgcn_mfma_f32_16x16x32_bf16(aH[i], bX[j], accY[i][j], 0, 0, 0);
        accY[i][j] = __builtin_amdgcn_mfma_f32_16x16x32_bf16(aL[i], bX[j], accY[i][j], 0, 0, 0);
      }
  }
  const float Dh = Dv[h];
  #pragma unroll
  for(int fi=0;fi<4;++fi){
    #pragma unroll
    for(int fj=0;fj<4;++fj){
      int p = wn*64 + fj*16 + ml;
      #pragma unroll
      for(int r=0;r<4;++r){
        int t = wm*64 + fi*16 + kg*4 + r;
        float* ap = &xs[(mb+t)*1536 + h*128 + p];
        float old = *ap;
        *ap = accY[fi][fj][r] + Dh*old;
      }
    }
  }
  __syncthreads();   // all waves done reading Cb (M_hi) before overwrite with Wt
  // ---- stage Wt = wB^T[n][j] = B[j][n]*exp(la127-la[j]) into Cb ----
  float laF = la[127];
  for(int a = tid; a < 2048; a += 256){
    int j = a >> 4, noct = a & 15;
    float wj = expf(laF - la[j]);
    int ck = j>>5, o = (j>>3)&3, e = j&7;
    #pragma unroll
    for(int q=0;q<8;++q){
      int n = noct*8+q;
      float v = bf2f(Bm[(mb+j)*128 + n]) * wj;
      Cb[ck*4096 + (n*4 + (o ^ ((n>>1)&3)))*8 + e] = f2bf(v);
    }
  }
  __syncthreads();
  // ---- GEMM3: S[n][p] = sum_j wB[j][n]*dtX[j][p] -> sfin ----
  f32x4 accS[4][4];
  #pragma unroll
  for(int i=0;i<4;++i)
    #pragma unroll
    for(int j=0;j<4;++j) accS[i][j] = (f32x4){0.f,0.f,0.f,0.f};
  for(int ck=0;ck<4;++ck){
    short8 aW[4], bX[4];
    #pragma unroll
    for(int f=0;f<4;++f){
      int row = wm*64 + f*16 + ml;
      aW[f] = *reinterpret_cast<const short8*>(Cb + ck*4096 + (row*4 + (kg ^ ((row>>1)&3)))*8);
      int rowp = wn*64 + f*16 + ml;
      bX[f] = *reinterpret_cast<const short8*>(Xt + ck*4096 + (rowp*4 + (kg ^ ((rowp>>1)&3)))*8);
    }
    #pragma unroll
    for(int i=0;i<4;++i)
      #pragma unroll
      for(int j=0;j<4;++j)
        accS[i][j] = __builtin_amdgcn_mfma_f32_16x16x32_bf16(aW[i], bX[j], accS[i][j], 0, 0, 0);
  }
  float* dst = sfin + (bh*8 + (size_t)c)*16384;
  #pragma unroll
  for(int fi=0;fi<4;++fi){
    #pragma unroll
    for(int fj=0;fj<4;++fj){
      int p = wn*64 + fj*16 + ml;
      #pragma unroll
      for(int r=0;r<4;++r){
        int n = wm*64 + fi*16 + kg*4 + r;
        dst[(size_t)n*128 + p] = accS[fi][fj][r];
      }
    }
  }
}

// ---------------- SSM pass 2: inter-chunk correction y += cumP * (C . S_init) ----------------
__global__ __launch_bounds__(256) void correct_k(const unsigned short* __restrict__ Cm,
    const float* __restrict__ cumdA, const float* __restrict__ sfin,
    float* __restrict__ ys){
  const int c = blockIdx.x + 1, h = blockIdx.y, b = blockIdx.z;
  const int tid = threadIdx.x;
  const size_t bh = (size_t)b*12 + h;
  __shared__ float Sl[16][128];
  __shared__ float Cl[16][132];
  __shared__ float cumP[128];
  __shared__ float coefs[8];
  if(tid==0){
    float cf = 1.f;
    for(int cp=c-1; cp>=0; --cp){
      coefs[cp] = cf;
      cf *= cumdA[bh*1024 + (size_t)cp*128 + 127];
    }
  }
  if(tid<128) cumP[tid] = cumdA[bh*1024 + (size_t)c*128 + tid];
  __syncthreads();
  const int tp = tid>>4, tt = tid&15;
  float acc[8][8];
  #pragma unroll
  for(int i=0;i<8;++i)
    #pragma unroll
    for(int j=0;j<8;++j) acc[i][j]=0.f;
  const size_t mb = (size_t)b*1024 + (size_t)c*128;
  for(int n0=0;n0<128;n0+=16){
    {
      int kk = tid>>4, po = tid&15;
      float4 v0 = {0,0,0,0}, v1 = {0,0,0,0};
      for(int cp=0; cp<c; ++cp){
        const float* sp = sfin + ((bh*8 + cp)*16384) + (size_t)(n0+kk)*128 + po*8;
        float4 a0 = *reinterpret_cast<const float4*>(sp);
        float4 a1 = *reinterpret_cast<const float4*>(sp+4);
        float cf = coefs[cp];
        v0.x = fmaf(cf,a0.x,v0.x); v0.y = fmaf(cf,a0.y,v0.y);
        v0.z = fmaf(cf,a0.z,v0.z); v0.w = fmaf(cf,a0.w,v0.w);
        v1.x = fmaf(cf,a1.x,v1.x); v1.y = fmaf(cf,a1.y,v1.y);
        v1.z = fmaf(cf,a1.z,v1.z); v1.w = fmaf(cf,a1.w,v1.w);
      }
      *reinterpret_cast<float4*>(&Sl[kk][po*8])   = v0;
      *reinterpret_cast<float4*>(&Sl[kk][po*8+4]) = v1;
    }
    #pragma unroll
    for(int e=0;e<8;++e){
      int idx = tid*8 + e; int tl = idx>>4, kk = idx&15;
      Cl[kk][tl] = bf2f(Cm[(mb + tl)*128 + n0 + kk]);
    }
    __syncthreads();
    #pragma unroll
    for(int kk=0;kk<16;++kk){
      float4 sa = *reinterpret_cast<const float4*>(&Sl[kk][tp*8]);
      float4 sb = *reinterpret_cast<const float4*>(&Sl[kk][tp*8+4]);
      float4 ca = *reinterpret_cast<const float4*>(&Cl[kk][tt*8]);
      float4 cb = *reinterpret_cast<const float4*>(&Cl[kk][tt*8+4]);
      float sv[8] = {sa.x,sa.y,sa.z,sa.w,sb.x,sb.y,sb.z,sb.w};
      float cv[8] = {ca.x,ca.y,ca.z,ca.w,cb.x,cb.y,cb.z,cb.w};
      #pragma unroll
      for(int i=0;i<8;++i)
        #pragma unroll
        for(int j=0;j<8;++j) acc[i][j] = fmaf(sv[i], cv[j], acc[i][j]);
    }
    __syncthreads();
  }
  #pragma unroll
  for(int j=0;j<8;++j){
    int tl = tt*8 + j;
    float cp = cumP[tl];
    float* yp = ys + (mb + tl)*1536 + h*128 + tp*8;
    float4 y0 = *reinterpret_cast<float4*>(yp);
    float4 y1 = *reinterpret_cast<float4*>(yp+4);
    y0.x += cp*acc[0][j]; y0.y += cp*acc[1][j]; y0.z += cp*acc[2][j]; y0.w += cp*acc[3][j];
    y1.x += cp*acc[4][j]; y1.y += cp*acc[5][j]; y1.z += cp*acc[6][j]; y1.w += cp*acc[7][j];
    *reinterpret_cast<float4*>(yp)   = y0;
    *reinterpret_cast<float4*>(yp+4) = y1;
  }
}

// ---------------- gating: y*silu(z), RMSNorm, partitioned mean-accumulate ----------------
__global__ void gate_k(const float* __restrict__ ys, const float* __restrict__ Z,
                       const float* __restrict__ nw, float* __restrict__ ybp){
  int m = blockIdx.x;
  int b = m >> 10, t = m & 1023;
  int tid = threadIdx.x;
  float gvals[6];
  float ss = 0.0f;
  #pragma unroll
  for(int r=0;r<6;++r){
    int c = r*256 + tid;
    float yv = ys[(size_t)m*1536 + c];
    float zv = Z[(size_t)m*1536 + c];
    float gv = yv * siluf(zv);
    gvals[r] = gv;
    ss = fmaf(gv, gv, ss);
  }
  #pragma unroll
  for(int off=32;off;off>>=1) ss += __shfl_xor(ss, off);
  __shared__ float red[4];
  if((tid&63)==0) red[tid>>6] = ss;
  __syncthreads();
  float tot = red[0]+red[1]+red[2]+red[3];
  float scale = rsqrtf(tot*(1.0f/1536.0f) + 1e-5f);
  float* dst = ybp + ((size_t)(t&7)*8 + b)*1536;
  #pragma unroll
  for(int r=0;r<6;++r){
    int c = r*256 + tid;
    atomicAdd(&dst[c], gvals[r]*scale*nw[c]);
  }
}

__global__ void ybm_k(const float* __restrict__ ybp, float* __restrict__ ybm){
  int idx = blockIdx.x*256 + threadIdx.x;
  float s = 0.0f;
  #pragma unroll
  for(int p=0;p<8;++p) s += ybp[(size_t)p*12288 + idx];
  ybm[idx] = s * (1.0f/1024.0f);
}

__global__ void rep_k(const float* __restrict__ ybm, const float* __restrict__ W,
                      float* __restrict__ rep){
  int wid  = (blockIdx.x<<2) + (threadIdx.x>>6);
  int lane = threadIdx.x & 63;
  int b = wid / 768, o = wid % 768;
  const float* xr = ybm + (size_t)b*1536;
  const float* wr = W + (size_t)o*1536;
  float acc = 0.0f;
  for(int c=lane;c<1536;c+=64) acc = fmaf(xr[c], wr[c], acc);
  #pragma unroll
  for(int off=32;off;off>>=1) acc += __shfl_xor(acc, off);
  if(lane==0) rep[wid] = acc;
}

__global__ void fc1_k(const float* __restrict__ rep, const float* __restrict__ W,
                      const float* __restrict__ bias, const float* __restrict__ g,
                      const float* __restrict__ bb, const float* __restrict__ m,
                      const float* __restrict__ v, float* __restrict__ out){
  int wid  = (blockIdx.x<<2) + (threadIdx.x>>6);
  int lane = threadIdx.x & 63;
  int b = wid >> 10, o = wid & 1023;
  const float* xr = rep + (size_t)b*768;
  const float* wr = W + (size_t)o*768;
  float acc = 0.0f;
  for(int c=lane;c<768;c+=64) acc = fmaf(xr[c], wr[c], acc);
  #pragma unroll
  for(int off=32;off;off>>=1) acc += __shfl_xor(acc, off);
  if(lane==0){
    float val = acc + bias[o];
    float sc = g[o]*rsqrtf(v[o]+1e-5f);
    val = (val - m[o])*sc + bb[o];
    out[wid] = fmaxf(val, 0.0f);
  }
}

__global__ void fc2_k(const float* __restrict__ h1, const float* __restrict__ W,
                      const float* __restrict__ bias, float* __restrict__ out){
  int wid  = (blockIdx.x<<2) + (threadIdx.x>>6);
  int lane = threadIdx.x & 63;
  int b = wid / 27, o = wid % 27;
  const float* xr = h1 + (size_t)b*1024;
  const float* wr = W + (size_t)o*1024;
  float acc = 0.0f;
  for(int c=lane;c<1024;c+=64) acc = fmaf(xr[c], wr[c], acc);
  #pragma unroll
  for(int off=32;off;off>>=1) acc += __shfl_xor(acc, off);
  if(lane==0) out[wid] = acc + bias[o];
}

// ---------------- workspace layout (float offsets) ----------------
// Footprint: 54,945,792 floats (proven cap).
#define OFF_H1     0u
#define OFF_T1     3145728u
#define OFF_T2     4718592u
#define OFF_H3T    6291456u
#define OFF_WB     9437184u
#define OFF_W2R    10715136u
#define OFF_W3R    10825728u
#define OFF_Z      12582912u
#define OFF_XB     25165824u
#define OFF_XS     39944192u
#define OFF_H3F    39944192u
#define OFF_B      52527104u    // now ushort[1,048,576] (half-used)
#define OFF_C      53575680u    // now ushort[1,048,576] (half-used)
#define OFF_DT     54624256u    // 98,304 (dt)
#define OFF_DA     54722560u    // 98,304 -> lab (log-cumsum)
#define OFF_SLOT98K 54820864u   // 98,304: cda (cumda->correct) then ybp (gate->ybm)
#define OFF_YBM    54919168u
#define OFF_REP    54931456u
#define OFF_FC1    54937600u
#define OFF_SFIN   0u           // 12,582,912 [ssd -> correct], early region dead

extern "C" void kernel_launch(void* const* d_in, const int* in_sizes, int n_in,
                              void* d_out, int out_size, void* d_ws, size_t ws_size,
                              hipStream_t stream){
  const float* x       = (const float*)d_in[0];
  const float* w1      = (const float*)d_in[1];
  const float* b1      = (const float*)d_in[2];
  const float* bn1g    = (const float*)d_in[3];
  const float* bn1b    = (const float*)d_in[4];
  const float* bn1m    = (const float*)d_in[5];
  const float* bn1v    = (const float*)d_in[6];
  const float* w2      = (const float*)d_in[7];
  const float* b2      = (const float*)d_in[8];
  const float* bn2g    = (const float*)d_in[9];
  const float* bn2b    = (const float*)d_in[10];
  const float* bn2m    = (const float*)d_in[11];
  const float* bn2v    = (const float*)d_in[12];
  const float* w3      = (const float*)d_in[13];
  const float* b3      = (const float*)d_in[14];
  const float* bn3g    = (const float*)d_in[15];
  const float* bn3b    = (const float*)d_in[16];
  const float* bn3m    = (const float*)d_in[17];
  const float* bn3v    = (const float*)d_in[18];
  const float* ipw     = (const float*)d_in[19];
  const float* convw   = (const float*)d_in[20];
  const float* convb   = (const float*)d_in[21];
  const float* dtbias  = (const float*)d_in[22];
  const float* Alog    = (const float*)d_in[23];
  const float* Dvec    = (const float*)d_in[24];
  const float* normw   = (const float*)d_in[25];
  const float* opw     = (const float*)d_in[26];
  const float* fc1w    = (const float*)d_in[27];
  const float* fc1b    = (const float*)d_in[28];
  const float* bncg    = (const float*)d_in[29];
  const float* bncb    = (const float*)d_in[30];
  const float* bncm    = (const float*)d_in[31];
  const float* bncv    = (const float*)d_in[32];
  const float* fc2w    = (const float*)d_in[33];
  const float* fc2b    = (const float*)d_in[34];

  float* ws   = (float*)d_ws;
  float* h1   = ws + OFF_H1;
  unsigned short* T1  = (unsigned short*)(ws + OFF_T1);
  unsigned short* T2  = (unsigned short*)(ws + OFF_T2);
  unsigned short* h3t = (unsigned short*)(ws + OFF_H3T);
  unsigned short* Wb  = (unsigned short*)(ws + OFF_WB);
  unsigned short* w2r = (unsigned short*)(ws + OFF_W2R);
  unsigned short* w3r = (unsigned short*)(ws + OFF_W3R);
  float* Zb   = ws + OFF_Z;
  float* XBb  = ws + OFF_XB;
  float* xsb  = ws + OFF_XS;
  float* h3f  = ws + OFF_H3F;
  unsigned short* Bo = (unsigned short*)(ws + OFF_B);
  unsigned short* Co = (unsigned short*)(ws + OFF_C);
  float* dtb  = ws + OFF_DT;
  float* lab  = ws + OFF_DA;
  float* slot = ws + OFF_SLOT98K;
  float* ybm  = ws + OFF_YBM;
  float* rep  = ws + OFF_REP;
  float* f1b  = ws + OFF_FC1;
  float* sfin = ws + OFF_SFIN;
  float* outp = (float*)d_out;

  conv1_k<<<dim3(8,24,8),  256, 0, stream>>>(x, w1, b1, bn1g, bn1b, bn1m, bn1v, h1);
  xpose1_k<<<dim3(64,6,8), 256, 0, stream>>>(h1, T1);
  wprep_k<<<14304, 256, 0, stream>>>(ipw, w2, w3, Wb, w2r, w3r);
  conv2_mfma<<<dim3(3,64), 256, 0, stream>>>(T1, w2r, b2, bn2g, bn2b, bn2m, bn2v, T2);
  conv3_mfma<<<dim3(6,64), 256, 0, stream>>>(T2, w3r, b3, bn3g, bn3b, bn3m, bn3v, h3t, h3f);
  dtgemm2_k<<<2048, 256, 0, stream>>>(h3f, ipw, dtbias, dtb);
  inproj_mfma<<<dim3(26,64), 256, 0, stream>>>(h3t, Wb, Zb, XBb);
  dwconv_k<<<14336, 256, 0, stream>>>(XBb, convw, convb, xsb, Bo, Co);
  cumda_k<<<96, 128, 0, stream>>>(dtb, Alog, slot, lab);             // cda = slot, lab
  ssd_k<<<dim3(8,12,8), 256, 0, stream>>>(xsb, Bo, Co, dtb, lab, Dvec, sfin);
  correct_k<<<dim3(7,12,8), 256, 0, stream>>>(Co, slot, sfin, xsb);  // reads cda
  hipMemsetAsync(slot, 0, 98304*sizeof(float), stream);              // zero ybp
  gate_k<<<8192, 256, 0, stream>>>(xsb, Zb, normw, slot);            // ybp = slot (atomics)
  ybm_k<<<48, 256, 0, stream>>>(slot, ybm);
  rep_k<<<1536, 256, 0, stream>>>(ybm, opw, rep);
  fc1_k<<<2048, 256, 0, stream>>>(rep, fc1w, fc1b, bncg, bncb, bncm, bncv, f1b);
  fc2_k<<<54, 256, 0, stream>>>(f1b, fc2w, fc2b, outp);
}